// Round 1
// baseline (705.245 us; speedup 1.0000x reference)
//
#include <hip/hip_runtime.h>

#define DIV_UP(a,b) (((a)+(b)-1)/(b))

// ---------------------------------------------------------------------------
// Edge-index access: harness may hand us int64 (reference dtype) or int32.
// Detect once on device: for little-endian int64 with values < 2^31, every
// odd 32-bit word is zero. mode=1 -> int64, mode=0 -> int32.
// ---------------------------------------------------------------------------
__device__ __forceinline__ int edge_at(const void* ei, int mode64, int idx) {
  if (mode64) return (int)((const long long*)ei)[idx];
  return ((const int*)ei)[idx];
}

__global__ void k_detect(const int* __restrict__ ei32, int* __restrict__ mode) {
  int t = threadIdx.x;                 // 64 threads
  int v = ei32[2 * t + 1];
  unsigned long long b = __ballot(v == 0);
  if (t == 0) *mode = (b == ~0ull) ? 1 : 0;
}

// deg[c] += 1 per edge (in-degree); self-loop added in k_dinv
__global__ __launch_bounds__(256) void k_deg(const void* __restrict__ ei,
                                             const int* __restrict__ mode,
                                             float* __restrict__ deg, int E) {
  int i = blockIdx.x * 256 + threadIdx.x;
  if (i < E) {
    int c = edge_at(ei, *mode, E + i);
    atomicAdd(&deg[c], 1.0f);
  }
}

__global__ __launch_bounds__(256) void k_dinv(const float* __restrict__ deg,
                                              float* __restrict__ dinv, int n) {
  int i = blockIdx.x * 256 + threadIdx.x;
  if (i < n) dinv[i] = rsqrtf(deg[i] + 1.0f);   // +1 = self loop; always > 0
}

// dst[n][f] = dinv[n]^2 * src[n][f] (+ bias[f])  -- self-loop term as init
template <int F>
__global__ __launch_bounds__(256) void k_self_init(const float* __restrict__ src,
                                                   const float* __restrict__ dinv,
                                                   const float* __restrict__ bias,
                                                   float* __restrict__ dst, int n) {
  int i = blockIdx.x * 256 + threadIdx.x;
  int total = n * F;
  if (i < total) {
    int node = i / F;
    int f = i - node * F;
    float d = dinv[node];
    float v = d * d * src[i];
    if (bias) v += bias[f];
    dst[i] = v;
  }
}

// dst[col][f] += dinv[row]*dinv[col] * src[row][f]   over all edges
template <int F>
__global__ __launch_bounds__(256) void k_scatter(const void* __restrict__ ei,
                                                 const int* __restrict__ mode,
                                                 const float* __restrict__ dinv,
                                                 const float* __restrict__ src,
                                                 float* __restrict__ dst, int E) {
  int total = E * F;                       // 80M / 51.2M: fits int32
  int stride = gridDim.x * 256;
  int m = *mode;
  for (int i = blockIdx.x * 256 + threadIdx.x; i < total; i += stride) {
    int e = i / F;                         // const divisor -> magic mul
    int f = i - e * F;
    int r = edge_at(ei, m, e);
    int c = edge_at(ei, m, E + e);
    float coef = dinv[r] * dinv[c];
    atomicAdd(&dst[c * F + f], coef * src[r * F + f]);
  }
}

// ---------------------------------------------------------------------------
// Y[n][j] = act( sum_k A[n][k] * W[k][j] + bias[j] )
// Register-blocked f32 GEMM: W staged in LDS, each thread computes
// NPT_N nodes x 4 output columns. JL = OUT/4 lanes cover the j dimension.
// ---------------------------------------------------------------------------
template <int IN, int OUT, int NPT_N, bool RELU>
__global__ __launch_bounds__(256) void k_linear(const float* __restrict__ A,
                                                const float* __restrict__ W,
                                                const float* __restrict__ bias,
                                                float* __restrict__ Y, int n) {
  constexpr int JL = OUT / 4;            // lanes along j
  constexpr int GROUPS = 256 / JL;       // node groups per block
  constexpr int ROWS = GROUPS * NPT_N;   // nodes per block
  __shared__ float sW[IN * OUT];
  __shared__ float sA[ROWS][IN + 1];     // +1 pad: avoid bank conflicts on group-strided reads

  for (int i = threadIdx.x; i < IN * OUT; i += 256) sW[i] = W[i];

  const int g = threadIdx.x / JL;
  const int jl = threadIdx.x - g * JL;
  const int nb = blockIdx.x * ROWS;

  for (int i = threadIdx.x; i < ROWS * IN; i += 256) {
    int rr = i / IN, cc = i - rr * IN;
    int node = nb + rr;
    sA[rr][cc] = (node < n) ? A[node * IN + cc] : 0.f;
  }
  __syncthreads();

  float acc[NPT_N][4];
#pragma unroll
  for (int i = 0; i < NPT_N; ++i)
#pragma unroll
    for (int m2 = 0; m2 < 4; ++m2) acc[i][m2] = 0.f;

#pragma unroll 4
  for (int k = 0; k < IN; ++k) {
    float w0 = sW[k * OUT + jl];
    float w1 = sW[k * OUT + jl + JL];
    float w2 = sW[k * OUT + jl + 2 * JL];
    float w3 = sW[k * OUT + jl + 3 * JL];
#pragma unroll
    for (int i = 0; i < NPT_N; ++i) {
      float a = sA[g * NPT_N + i][k];
      acc[i][0] += a * w0;
      acc[i][1] += a * w1;
      acc[i][2] += a * w2;
      acc[i][3] += a * w3;
    }
  }

#pragma unroll
  for (int i = 0; i < NPT_N; ++i) {
    int node = nb + g * NPT_N + i;
    if (node < n) {
#pragma unroll
      for (int m2 = 0; m2 < 4; ++m2) {
        int j = m2 * JL + jl;
        float v = acc[i][m2] + (bias ? bias[j] : 0.f);
        if (RELU) v = fmaxf(v, 0.f);
        Y[node * OUT + j] = v;
      }
    }
  }
}

// ---------------------------------------------------------------------------
extern "C" void kernel_launch(void* const* d_in, const int* in_sizes, int n_in,
                              void* d_out, int out_size, void* d_ws, size_t ws_size,
                              hipStream_t stream) {
  const float* x  = (const float*)d_in[0];
  const void*  ei = d_in[1];
  const float* W1 = (const float*)d_in[2];
  const float* b1 = (const float*)d_in[3];
  const float* W2 = (const float*)d_in[4];
  const float* b2 = (const float*)d_in[5];
  float* out = (float*)d_out;

  const int n = in_sizes[0] / 100;   // 50000
  const int E = in_sizes[1] / 2;     // 800000

  // ws layout (floats): [mode pad 64][deg n][dinv n][agg n*100 (reused as t n*64)][h1 n*128]
  float* wsf  = (float*)d_ws;
  int*   mode = (int*)d_ws;
  float* deg  = wsf + 64;
  float* dinv = deg + n;
  float* agg  = dinv + n;            // n*100; later reused for t (n*64)
  float* h1   = agg + n * 100;       // n*128
  float* t    = agg;                 // alias: agg dead after gemm1

  k_detect<<<1, 64, 0, stream>>>((const int*)ei, mode);
  hipMemsetAsync(deg, 0, (size_t)n * sizeof(float), stream);
  k_deg<<<DIV_UP(E, 256), 256, 0, stream>>>(ei, mode, deg, E);
  k_dinv<<<DIV_UP(n, 256), 256, 0, stream>>>(deg, dinv, n);

  // Layer 1: aggregate x (100-dim) first, then h1 = relu(agg @ W1 + b1)
  k_self_init<100><<<DIV_UP(n * 100, 256), 256, 0, stream>>>(x, dinv, nullptr, agg, n);
  k_scatter<100><<<4096, 256, 0, stream>>>(ei, mode, dinv, x, agg, E);
  k_linear<100, 128, 4, true><<<DIV_UP(n, 32), 256, 0, stream>>>(agg, W1, b1, h1, n);

  // Layer 2: transform first t = h1 @ W2 (64-dim), then aggregate into out
  k_linear<128, 64, 2, false><<<DIV_UP(n, 32), 256, 0, stream>>>(h1, W2, nullptr, t, n);
  k_self_init<64><<<DIV_UP(n * 64, 256), 256, 0, stream>>>(t, dinv, b2, out, n);
  k_scatter<64><<<4096, 256, 0, stream>>>(ei, mode, dinv, t, out, E);
}

// Round 2
// 291.595 us; speedup vs baseline: 2.4186x; 2.4186x over previous
//
#include <hip/hip_runtime.h>

#define DIV_UP(a,b) (((a)+(b)-1)/(b))

// ---------------------------------------------------------------------------
// Edge-index access: harness may hand us int64 (reference dtype) or int32.
// Detect once on device: little-endian int64 with values < 2^31 has every
// odd 32-bit word zero. mode=1 -> int64, mode=0 -> int32.
// ---------------------------------------------------------------------------
__device__ __forceinline__ int edge_at(const void* ei, int mode64, int idx) {
  if (mode64) return (int)((const long long*)ei)[idx];
  return ((const int*)ei)[idx];
}

__global__ void k_detect(const int* __restrict__ ei32, int* __restrict__ mode) {
  int t = threadIdx.x;                 // 64 threads
  int v = ei32[2 * t + 1];
  unsigned long long b = __ballot(v == 0);
  if (t == 0) *mode = (b == ~0ull) ? 1 : 0;
}

// In-degree histogram (int)
__global__ __launch_bounds__(256) void k_deg(const void* __restrict__ ei,
                                             const int* __restrict__ mode,
                                             int* __restrict__ deg, int E) {
  int i = blockIdx.x * 256 + threadIdx.x;
  if (i < E) {
    int c = edge_at(ei, *mode, E + i);
    atomicAdd(&deg[c], 1);
  }
}

__global__ __launch_bounds__(256) void k_dinv(const int* __restrict__ deg,
                                              float* __restrict__ dinv, int n) {
  int i = blockIdx.x * 256 + threadIdx.x;
  if (i < n) dinv[i] = rsqrtf((float)deg[i] + 1.0f);   // +1 = self loop
}

// ---------------- prefix scan (3 kernels), 1024 elements/block -------------
__global__ __launch_bounds__(256) void k_scan1(const int* __restrict__ deg,
                                               int* __restrict__ local,
                                               int* __restrict__ bsum, int n) {
  __shared__ int s[256];
  int tid = threadIdx.x;
  int base = blockIdx.x * 1024 + tid * 4;
  int v0 = (base + 0 < n) ? deg[base + 0] : 0;
  int v1 = (base + 1 < n) ? deg[base + 1] : 0;
  int v2 = (base + 2 < n) ? deg[base + 2] : 0;
  int v3 = (base + 3 < n) ? deg[base + 3] : 0;
  int tsum = v0 + v1 + v2 + v3;
  s[tid] = tsum;
  __syncthreads();
#pragma unroll
  for (int off = 1; off < 256; off <<= 1) {
    int t = (tid >= off) ? s[tid - off] : 0;
    __syncthreads();
    s[tid] += t;
    __syncthreads();
  }
  int excl = s[tid] - tsum;
  if (tid == 255) bsum[blockIdx.x] = s[255];
  if (base + 0 < n) local[base + 0] = excl;
  if (base + 1 < n) local[base + 1] = excl + v0;
  if (base + 2 < n) local[base + 2] = excl + v0 + v1;
  if (base + 3 < n) local[base + 3] = excl + v0 + v1 + v2;
}

__global__ __launch_bounds__(256) void k_scan2(int* __restrict__ bsum, int nb) {
  __shared__ int s[256];
  int tid = threadIdx.x;
  int v = (tid < nb) ? bsum[tid] : 0;
  s[tid] = v;
  __syncthreads();
#pragma unroll
  for (int off = 1; off < 256; off <<= 1) {
    int t = (tid >= off) ? s[tid - off] : 0;
    __syncthreads();
    s[tid] += t;
    __syncthreads();
  }
  if (tid < nb) bsum[tid] = s[tid] - v;   // exclusive
}

__global__ __launch_bounds__(256) void k_scan3(int* __restrict__ rowstart,
                                               const int* __restrict__ bsum,
                                               int* __restrict__ cursor,
                                               int n, int E) {
  int i = blockIdx.x * 256 + threadIdx.x;
  if (i < n) {
    int v = rowstart[i] + bsum[i >> 10];
    rowstart[i] = v;
    cursor[i] = v;
  }
  if (i == n) rowstart[n] = E;
}

// CSR fill: csr[pos] = (src, coef)
__global__ __launch_bounds__(256) void k_fill(const void* __restrict__ ei,
                                              const int* __restrict__ mode,
                                              const float* __restrict__ dinv,
                                              int* __restrict__ cursor,
                                              int2* __restrict__ csr, int E) {
  int i = blockIdx.x * 256 + threadIdx.x;
  if (i < E) {
    int m = *mode;
    int r = edge_at(ei, m, i);
    int c = edge_at(ei, m, E + i);
    int pos = atomicAdd(&cursor[c], 1);
    csr[pos] = make_int2(r, __float_as_int(dinv[r] * dinv[c]));
  }
}

// ---------------------------------------------------------------------------
// Pull aggregation: V float4 lanes per node (V = F/4).
// acc = dinv[node]^2 * src[node] (+bias); then += coef * src[r] over in-edges.
// ---------------------------------------------------------------------------
template <int V, int G>   // G = groups per 256-thread block
__global__ __launch_bounds__(256) void k_pull(const int* __restrict__ rowstart,
                                              const int2* __restrict__ csr,
                                              const float* __restrict__ dinv,
                                              const float4* __restrict__ src4,
                                              const float4* __restrict__ bias4,
                                              float4* __restrict__ dst4, int n) {
  int g = threadIdx.x / V;
  int lane = threadIdx.x - g * V;
  int node = blockIdx.x * G + g;
  if (g >= G || node >= n) return;

  float dc = dinv[node];
  float4 sv = src4[(long)node * V + lane];
  float4 acc;
  float s2 = dc * dc;
  acc.x = s2 * sv.x; acc.y = s2 * sv.y; acc.z = s2 * sv.z; acc.w = s2 * sv.w;
  if (bias4) {
    float4 b = bias4[lane];
    acc.x += b.x; acc.y += b.y; acc.z += b.z; acc.w += b.w;
  }

  int beg = rowstart[node], end = rowstart[node + 1];
  for (int j = beg; j < end; ++j) {
    int2 rc = csr[j];
    float coef = __int_as_float(rc.y);
    float4 xv = src4[(long)rc.x * V + lane];
    acc.x += coef * xv.x; acc.y += coef * xv.y;
    acc.z += coef * xv.z; acc.w += coef * xv.w;
  }
  dst4[(long)node * V + lane] = acc;
}

// ---------------------------------------------------------------------------
// Y[n][j] = act( sum_k A[n][k] * W[k][j] + bias[j] ) — W in LDS, reg-blocked
// ---------------------------------------------------------------------------
template <int IN, int OUT, int NPT_N, bool RELU>
__global__ __launch_bounds__(256) void k_linear(const float* __restrict__ A,
                                                const float* __restrict__ W,
                                                const float* __restrict__ bias,
                                                float* __restrict__ Y, int n) {
  constexpr int JL = OUT / 4;
  constexpr int GROUPS = 256 / JL;
  constexpr int ROWS = GROUPS * NPT_N;
  __shared__ float sW[IN * OUT];
  __shared__ float sA[ROWS][IN + 1];

  for (int i = threadIdx.x; i < IN * OUT; i += 256) sW[i] = W[i];

  const int g = threadIdx.x / JL;
  const int jl = threadIdx.x - g * JL;
  const int nb = blockIdx.x * ROWS;

  for (int i = threadIdx.x; i < ROWS * IN; i += 256) {
    int rr = i / IN, cc = i - rr * IN;
    int node = nb + rr;
    sA[rr][cc] = (node < n) ? A[node * IN + cc] : 0.f;
  }
  __syncthreads();

  float acc[NPT_N][4];
#pragma unroll
  for (int i = 0; i < NPT_N; ++i)
#pragma unroll
    for (int m2 = 0; m2 < 4; ++m2) acc[i][m2] = 0.f;

#pragma unroll 4
  for (int k = 0; k < IN; ++k) {
    float w0 = sW[k * OUT + jl];
    float w1 = sW[k * OUT + jl + JL];
    float w2 = sW[k * OUT + jl + 2 * JL];
    float w3 = sW[k * OUT + jl + 3 * JL];
#pragma unroll
    for (int i = 0; i < NPT_N; ++i) {
      float a = sA[g * NPT_N + i][k];
      acc[i][0] += a * w0;
      acc[i][1] += a * w1;
      acc[i][2] += a * w2;
      acc[i][3] += a * w3;
    }
  }

#pragma unroll
  for (int i = 0; i < NPT_N; ++i) {
    int node = nb + g * NPT_N + i;
    if (node < n) {
#pragma unroll
      for (int m2 = 0; m2 < 4; ++m2) {
        int j = m2 * JL + jl;
        float v = acc[i][m2] + (bias ? bias[j] : 0.f);
        if (RELU) v = fmaxf(v, 0.f);
        Y[node * OUT + j] = v;
      }
    }
  }
}

// ---------------------------------------------------------------------------
extern "C" void kernel_launch(void* const* d_in, const int* in_sizes, int n_in,
                              void* d_out, int out_size, void* d_ws, size_t ws_size,
                              hipStream_t stream) {
  const float* x  = (const float*)d_in[0];
  const void*  ei = d_in[1];
  const float* W1 = (const float*)d_in[2];
  const float* b1 = (const float*)d_in[3];
  const float* W2 = (const float*)d_in[4];
  const float* b2 = (const float*)d_in[5];
  float* out = (float*)d_out;

  const int n = in_sizes[0] / 100;   // 50000
  const int E = in_sizes[1] / 2;     // 800000
  const int NB = DIV_UP(n, 1024);    // scan blocks (49)

  // ws layout (4-byte units, all offsets kept multiple-of-4 for float4/int2)
  char* ws = (char*)d_ws;
  size_t off = 0;
  auto alloc = [&](size_t elems) { void* p = ws + off * 4; off += (elems + 3) & ~3ull; return p; };
  int*   mode     = (int*)  alloc(64);
  int*   deg      = (int*)  alloc(n);        // reused as cursor
  float* dinv     = (float*)alloc(n);
  int*   rowstart = (int*)  alloc(n + 4);
  int*   bsum     = (int*)  alloc(256);
  int2*  csr      = (int2*) alloc(2 * (size_t)E);
  float* agg      = (float*)alloc((size_t)n * 100);  // reused as t (n*64)
  float* h1       = (float*)alloc((size_t)n * 128);
  float* t        = agg;
  int*   cursor   = deg;

  k_detect<<<1, 64, 0, stream>>>((const int*)ei, mode);
  hipMemsetAsync(deg, 0, (size_t)n * sizeof(int), stream);
  k_deg<<<DIV_UP(E, 256), 256, 0, stream>>>(ei, mode, deg, E);
  k_dinv<<<DIV_UP(n, 256), 256, 0, stream>>>(deg, dinv, n);

  // CSR by destination
  k_scan1<<<NB, 256, 0, stream>>>(deg, rowstart, bsum, n);
  k_scan2<<<1, 256, 0, stream>>>(bsum, NB);
  k_scan3<<<DIV_UP(n + 1, 256), 256, 0, stream>>>(rowstart, bsum, cursor, n, E);
  k_fill<<<DIV_UP(E, 256), 256, 0, stream>>>(ei, mode, dinv, cursor, csr, E);

  // Layer 1: aggregate x (100-dim) via pull, then h1 = relu(agg @ W1 + b1)
  k_pull<25, 10><<<DIV_UP(n, 10), 256, 0, stream>>>(rowstart, csr, dinv,
      (const float4*)x, nullptr, (float4*)agg, n);
  k_linear<100, 128, 4, true><<<DIV_UP(n, 32), 256, 0, stream>>>(agg, W1, b1, h1, n);

  // Layer 2: t = h1 @ W2, then pull-aggregate into out (+b2)
  k_linear<128, 64, 2, false><<<DIV_UP(n, 32), 256, 0, stream>>>(h1, W2, nullptr, t, n);
  k_pull<16, 16><<<DIV_UP(n, 16), 256, 0, stream>>>(rowstart, csr, dinv,
      (const float4*)t, (const float4*)b2, (float4*)out, n);
}

// Round 3
// 247.605 us; speedup vs baseline: 2.8483x; 1.1777x over previous
//
#include <hip/hip_runtime.h>
#include <hip/hip_fp16.h>

#define DIV_UP(a,b) (((a)+(b)-1)/(b))

// NOTE: CSR entries are ushort (source node id) — valid because N_NODES=50000 < 65536.

// ---------------------------------------------------------------------------
// Edge-index dtype detection (int64 vs int32), as before.
// ---------------------------------------------------------------------------
__device__ __forceinline__ int edge_at(const void* ei, int mode64, int idx) {
  if (mode64) return (int)((const long long*)ei)[idx];
  return ((const int*)ei)[idx];
}

__global__ void k_detect(const int* __restrict__ ei32, int* __restrict__ mode) {
  int t = threadIdx.x;                 // 64 threads
  int v = ei32[2 * t + 1];
  unsigned long long b = __ballot(v == 0);
  if (t == 0) *mode = (b == ~0ull) ? 1 : 0;
}

__global__ __launch_bounds__(256) void k_deg(const void* __restrict__ ei,
                                             const int* __restrict__ mode,
                                             int* __restrict__ deg, int E) {
  int i = blockIdx.x * 256 + threadIdx.x;
  if (i < E) {
    int c = edge_at(ei, *mode, E + i);
    atomicAdd(&deg[c], 1);
  }
}

__global__ __launch_bounds__(256) void k_dinv(const int* __restrict__ deg,
                                              float* __restrict__ dinv, int n) {
  int i = blockIdx.x * 256 + threadIdx.x;
  if (i < n) dinv[i] = rsqrtf((float)deg[i] + 1.0f);   // +1 = self loop
}

// xh[node][f] = fp16( dinv[node] * x[node][f] )  — float4-granular
__global__ __launch_bounds__(256) void k_convx(const float4* __restrict__ x4,
                                               const float* __restrict__ dinv,
                                               uint2* __restrict__ xh4, int total4) {
  int i = blockIdx.x * 256 + threadIdx.x;
  if (i < total4) {
    int node = i / 25;                 // 25 float4 per 100-f row
    float d = dinv[node];
    float4 v = x4[i];
    union { uint2 u; __half2 h[2]; } p;
    p.h[0] = __halves2half2(__float2half_rn(d * v.x), __float2half_rn(d * v.y));
    p.h[1] = __halves2half2(__float2half_rn(d * v.z), __float2half_rn(d * v.w));
    xh4[i] = p.u;
  }
}

// ---------------- prefix scan (3 kernels), 1024 elements/block -------------
__global__ __launch_bounds__(256) void k_scan1(const int* __restrict__ deg,
                                               int* __restrict__ local,
                                               int* __restrict__ bsum, int n) {
  __shared__ int s[256];
  int tid = threadIdx.x;
  int base = blockIdx.x * 1024 + tid * 4;
  int v0 = (base + 0 < n) ? deg[base + 0] : 0;
  int v1 = (base + 1 < n) ? deg[base + 1] : 0;
  int v2 = (base + 2 < n) ? deg[base + 2] : 0;
  int v3 = (base + 3 < n) ? deg[base + 3] : 0;
  int tsum = v0 + v1 + v2 + v3;
  s[tid] = tsum;
  __syncthreads();
#pragma unroll
  for (int off = 1; off < 256; off <<= 1) {
    int t = (tid >= off) ? s[tid - off] : 0;
    __syncthreads();
    s[tid] += t;
    __syncthreads();
  }
  int excl = s[tid] - tsum;
  if (tid == 255) bsum[blockIdx.x] = s[255];
  if (base + 0 < n) local[base + 0] = excl;
  if (base + 1 < n) local[base + 1] = excl + v0;
  if (base + 2 < n) local[base + 2] = excl + v0 + v1;
  if (base + 3 < n) local[base + 3] = excl + v0 + v1 + v2;
}

__global__ __launch_bounds__(256) void k_scan2(int* __restrict__ bsum, int nb) {
  __shared__ int s[256];
  int tid = threadIdx.x;
  int v = (tid < nb) ? bsum[tid] : 0;
  s[tid] = v;
  __syncthreads();
#pragma unroll
  for (int off = 1; off < 256; off <<= 1) {
    int t = (tid >= off) ? s[tid - off] : 0;
    __syncthreads();
    s[tid] += t;
    __syncthreads();
  }
  if (tid < nb) bsum[tid] = s[tid] - v;   // exclusive
}

__global__ __launch_bounds__(256) void k_scan3(int* __restrict__ rowstart,
                                               const int* __restrict__ bsum,
                                               int* __restrict__ cursor,
                                               int n, int E) {
  int i = blockIdx.x * 256 + threadIdx.x;
  if (i < n) {
    int v = rowstart[i] + bsum[i >> 10];
    rowstart[i] = v;
    cursor[i] = v;
  }
  if (i == n) rowstart[n] = E;
}

// CSR fill: csr[pos] = src node id (ushort)
__global__ __launch_bounds__(256) void k_fill(const void* __restrict__ ei,
                                              const int* __restrict__ mode,
                                              int* __restrict__ cursor,
                                              unsigned short* __restrict__ csr, int E) {
  int i = blockIdx.x * 256 + threadIdx.x;
  if (i < E) {
    int m = *mode;
    int r = edge_at(ei, m, i);
    int c = edge_at(ei, m, E + i);
    int pos = atomicAdd(&cursor[c], 1);
    csr[pos] = (unsigned short)r;
  }
}

// ---------------------------------------------------------------------------
__device__ __forceinline__ float4 h4_to_f4(uint2 u) {
  union { uint2 u; __half2 h[2]; } p; p.u = u;
  float2 a = __half22float2(p.h[0]);
  float2 b = __half22float2(p.h[1]);
  return make_float4(a.x, a.y, b.x, b.y);
}

// Layer-1 pull: agg_h[c] = fp16( dinv[c] * (xh[c] + sum_{edges} xh[r]) )
// 25 lanes/node, 4 halves (8 B) per lane. 10 nodes per 256-thread block.
__global__ __launch_bounds__(256) void k_pull1(const int* __restrict__ rowstart,
                                               const unsigned short* __restrict__ csr,
                                               const uint2* __restrict__ xh4,
                                               const float* __restrict__ dinv,
                                               uint2* __restrict__ aggh4, int n) {
  int g = threadIdx.x / 25;
  int lane = threadIdx.x - g * 25;
  if (g >= 10) return;
  int node = blockIdx.x * 10 + g;
  if (node >= n) return;

  float4 acc = h4_to_f4(xh4[node * 25 + lane]);    // self term (dinv[c]*x[c])
  int beg = rowstart[node], end = rowstart[node + 1];
  int j = beg;
  for (; j + 1 < end; j += 2) {
    int r0 = csr[j], r1 = csr[j + 1];
    float4 a = h4_to_f4(xh4[r0 * 25 + lane]);
    float4 b = h4_to_f4(xh4[r1 * 25 + lane]);
    acc.x += a.x + b.x; acc.y += a.y + b.y;
    acc.z += a.z + b.z; acc.w += a.w + b.w;
  }
  if (j < end) {
    float4 a = h4_to_f4(xh4[(int)csr[j] * 25 + lane]);
    acc.x += a.x; acc.y += a.y; acc.z += a.z; acc.w += a.w;
  }
  float d = dinv[node];
  union { uint2 u; __half2 h[2]; } p;
  p.h[0] = __halves2half2(__float2half_rn(d * acc.x), __float2half_rn(d * acc.y));
  p.h[1] = __halves2half2(__float2half_rn(d * acc.z), __float2half_rn(d * acc.w));
  aggh4[node * 25 + lane] = p.u;
}

// Layer-2 pull: out[c] = dinv[c] * (th[c] + sum th[r]) + b2
// 8 lanes/node, 8 halves (16 B) per lane. 32 nodes per 256-thread block.
__global__ __launch_bounds__(256) void k_pull2(const int* __restrict__ rowstart,
                                               const unsigned short* __restrict__ csr,
                                               const uint4* __restrict__ th4,
                                               const float* __restrict__ dinv,
                                               const float4* __restrict__ b2_4,
                                               float4* __restrict__ out4, int n) {
  int g = threadIdx.x >> 3;
  int lane = threadIdx.x & 7;
  int node = blockIdx.x * 32 + g;
  if (node >= n) return;

  uint4 sv = th4[node * 8 + lane];
  float4 acc0 = h4_to_f4(make_uint2(sv.x, sv.y));
  float4 acc1 = h4_to_f4(make_uint2(sv.z, sv.w));

  int beg = rowstart[node], end = rowstart[node + 1];
  int j = beg;
  for (; j + 1 < end; j += 2) {
    uint4 u0 = th4[(int)csr[j] * 8 + lane];
    uint4 u1 = th4[(int)csr[j + 1] * 8 + lane];
    float4 a0 = h4_to_f4(make_uint2(u0.x, u0.y));
    float4 a1 = h4_to_f4(make_uint2(u0.z, u0.w));
    float4 b0 = h4_to_f4(make_uint2(u1.x, u1.y));
    float4 b1 = h4_to_f4(make_uint2(u1.z, u1.w));
    acc0.x += a0.x + b0.x; acc0.y += a0.y + b0.y;
    acc0.z += a0.z + b0.z; acc0.w += a0.w + b0.w;
    acc1.x += a1.x + b1.x; acc1.y += a1.y + b1.y;
    acc1.z += a1.z + b1.z; acc1.w += a1.w + b1.w;
  }
  if (j < end) {
    uint4 u0 = th4[(int)csr[j] * 8 + lane];
    float4 a0 = h4_to_f4(make_uint2(u0.x, u0.y));
    float4 a1 = h4_to_f4(make_uint2(u0.z, u0.w));
    acc0.x += a0.x; acc0.y += a0.y; acc0.z += a0.z; acc0.w += a0.w;
    acc1.x += a1.x; acc1.y += a1.y; acc1.z += a1.z; acc1.w += a1.w;
  }
  float d = dinv[node];
  float4 bb0 = b2_4[lane * 2], bb1 = b2_4[lane * 2 + 1];
  out4[node * 16 + lane * 2]     = make_float4(d * acc0.x + bb0.x, d * acc0.y + bb0.y,
                                               d * acc0.z + bb0.z, d * acc0.w + bb0.w);
  out4[node * 16 + lane * 2 + 1] = make_float4(d * acc1.x + bb1.x, d * acc1.y + bb1.y,
                                               d * acc1.z + bb1.z, d * acc1.w + bb1.w);
}

// ---------------------------------------------------------------------------
// Y[n][j] = act( sum_k A[n][k]*W[k][j] + bias[j] ) [* dinv[n] if SCALE]
// half or float in/out; W in LDS; reg-blocked NPT_N nodes x 4 cols per thread.
// ---------------------------------------------------------------------------
__device__ __forceinline__ float ld_f(const float* p) { return *p; }
__device__ __forceinline__ float ld_f(const __half* p) { return __half2float(*p); }
__device__ __forceinline__ void st_f(float* p, float v) { *p = v; }
__device__ __forceinline__ void st_f(__half* p, float v) { *p = __float2half_rn(v); }

template <int IN, int OUT, int NPT_N, bool RELU, bool SCALE, typename InT, typename OutT>
__global__ __launch_bounds__(256) void k_linear(const InT* __restrict__ A,
                                                const float* __restrict__ W,
                                                const float* __restrict__ bias,
                                                const float* __restrict__ dinv,
                                                OutT* __restrict__ Y, int n) {
  constexpr int JL = OUT / 4;
  constexpr int GROUPS = 256 / JL;
  constexpr int ROWS = GROUPS * NPT_N;
  __shared__ float sW[IN * OUT];
  __shared__ float sA[ROWS][IN + 1];

  for (int i = threadIdx.x; i < IN * OUT; i += 256) sW[i] = W[i];

  const int g = threadIdx.x / JL;
  const int jl = threadIdx.x - g * JL;
  const int nb = blockIdx.x * ROWS;

  for (int i = threadIdx.x; i < ROWS * IN; i += 256) {
    int rr = i / IN, cc = i - rr * IN;
    int node = nb + rr;
    sA[rr][cc] = (node < n) ? ld_f(&A[(size_t)node * IN + cc]) : 0.f;
  }
  __syncthreads();

  float acc[NPT_N][4];
#pragma unroll
  for (int i = 0; i < NPT_N; ++i)
#pragma unroll
    for (int m2 = 0; m2 < 4; ++m2) acc[i][m2] = 0.f;

#pragma unroll 4
  for (int k = 0; k < IN; ++k) {
    float w0 = sW[k * OUT + jl];
    float w1 = sW[k * OUT + jl + JL];
    float w2 = sW[k * OUT + jl + 2 * JL];
    float w3 = sW[k * OUT + jl + 3 * JL];
#pragma unroll
    for (int i = 0; i < NPT_N; ++i) {
      float a = sA[g * NPT_N + i][k];
      acc[i][0] += a * w0;
      acc[i][1] += a * w1;
      acc[i][2] += a * w2;
      acc[i][3] += a * w3;
    }
  }

#pragma unroll
  for (int i = 0; i < NPT_N; ++i) {
    int node = nb + g * NPT_N + i;
    if (node < n) {
      float sc = SCALE ? dinv[node] : 1.f;
#pragma unroll
      for (int m2 = 0; m2 < 4; ++m2) {
        int j = m2 * JL + jl;
        float v = acc[i][m2] + (bias ? bias[j] : 0.f);
        if (RELU) v = fmaxf(v, 0.f);
        v *= sc;
        st_f(&Y[(size_t)node * OUT + j], v);
      }
    }
  }
}

// ---------------------------------------------------------------------------
extern "C" void kernel_launch(void* const* d_in, const int* in_sizes, int n_in,
                              void* d_out, int out_size, void* d_ws, size_t ws_size,
                              hipStream_t stream) {
  const float* x  = (const float*)d_in[0];
  const void*  ei = d_in[1];
  const float* W1 = (const float*)d_in[2];
  const float* b1 = (const float*)d_in[3];
  const float* W2 = (const float*)d_in[4];
  const float* b2 = (const float*)d_in[5];
  float* out = (float*)d_out;

  const int n = in_sizes[0] / 100;   // 50000 (< 65536: ushort CSR valid)
  const int E = in_sizes[1] / 2;     // 800000
  const int NB = DIV_UP(n, 1024);    // scan blocks (49)

  // byte allocator, 16B-aligned
  char* ws = (char*)d_ws;
  size_t off = 0;
  auto alloc = [&](size_t bytes) { void* p = ws + off; off += (bytes + 15) & ~15ull; return p; };
  int*            mode     = (int*)   alloc(64 * 4);
  int*            deg      = (int*)   alloc((size_t)n * 4);     // reused as cursor
  float*          dinv     = (float*) alloc((size_t)n * 4);
  int*            rowstart = (int*)   alloc(((size_t)n + 4) * 4);
  int*            bsum     = (int*)   alloc(256 * 4);
  unsigned short* csr      = (unsigned short*)alloc((size_t)E * 2);
  __half*         xh       = (__half*)alloc((size_t)n * 100 * 2);
  __half*         aggh     = (__half*)alloc((size_t)n * 100 * 2);
  __half*         h1h      = (__half*)alloc((size_t)n * 128 * 2);
  __half*         thh      = (__half*)alloc((size_t)n * 64 * 2);
  int*            cursor   = deg;

  k_detect<<<1, 64, 0, stream>>>((const int*)ei, mode);
  hipMemsetAsync(deg, 0, (size_t)n * sizeof(int), stream);
  k_deg<<<DIV_UP(E, 256), 256, 0, stream>>>(ei, mode, deg, E);
  k_dinv<<<DIV_UP(n, 256), 256, 0, stream>>>(deg, dinv, n);
  k_convx<<<DIV_UP(n * 25, 256), 256, 0, stream>>>((const float4*)x, dinv, (uint2*)xh, n * 25);

  // CSR by destination (ushort source ids)
  k_scan1<<<NB, 256, 0, stream>>>(deg, rowstart, bsum, n);
  k_scan2<<<1, 256, 0, stream>>>(bsum, NB);
  k_scan3<<<DIV_UP(n + 1, 256), 256, 0, stream>>>(rowstart, bsum, cursor, n, E);
  k_fill<<<DIV_UP(E, 256), 256, 0, stream>>>(ei, mode, cursor, csr, E);

  // Layer 1: pull (fp16) -> h1 = relu(agg @ W1 + b1)  (agg,h1 fp16)
  k_pull1<<<DIV_UP(n, 10), 256, 0, stream>>>(rowstart, csr, (const uint2*)xh, dinv,
                                             (uint2*)aggh, n);
  k_linear<100, 128, 4, true, false, __half, __half>
      <<<DIV_UP(n, 32), 256, 0, stream>>>(aggh, W1, b1, nullptr, h1h, n);

  // Layer 2: th = dinv * (h1 @ W2)  (fp16), then pull -> out (f32, +b2)
  k_linear<128, 64, 2, false, true, __half, __half>
      <<<DIV_UP(n, 32), 256, 0, stream>>>(h1h, W2, nullptr, dinv, thh, n);
  k_pull2<<<DIV_UP(n, 32), 256, 0, stream>>>(rowstart, csr, (const uint4*)thh, dinv,
                                             (const float4*)b2, (float4*)out, n);
}

// Round 4
// 187.817 us; speedup vs baseline: 3.7550x; 1.3183x over previous
//
#include <hip/hip_runtime.h>
#include <hip/hip_fp16.h>

#define DIV_UP(a,b) (((a)+(b)-1)/(b))

typedef _Float16 half8 __attribute__((ext_vector_type(8)));
typedef float f32x4 __attribute__((ext_vector_type(4)));

// NOTE: CSR entries are ushort (source node id) — valid because N_NODES=50000 < 65536.

// ---------------------------------------------------------------------------
// Edge-index dtype detection (int64 vs int32).
// ---------------------------------------------------------------------------
__device__ __forceinline__ int edge_at(const void* ei, int mode64, int idx) {
  if (mode64) return (int)((const long long*)ei)[idx];
  return ((const int*)ei)[idx];
}

__global__ void k_detect(const int* __restrict__ ei32, int* __restrict__ mode) {
  int t = threadIdx.x;                 // 64 threads
  int v = ei32[2 * t + 1];
  unsigned long long b = __ballot(v == 0);
  if (t == 0) *mode = (b == ~0ull) ? 1 : 0;
}

__global__ __launch_bounds__(256) void k_deg(const void* __restrict__ ei,
                                             const int* __restrict__ mode,
                                             int* __restrict__ deg, int E) {
  int i = blockIdx.x * 256 + threadIdx.x;
  if (i < E) {
    int c = edge_at(ei, *mode, E + i);
    atomicAdd(&deg[c], 1);
  }
}

__global__ __launch_bounds__(256) void k_dinv(const int* __restrict__ deg,
                                              float* __restrict__ dinv, int n) {
  int i = blockIdx.x * 256 + threadIdx.x;
  if (i < n) dinv[i] = rsqrtf((float)deg[i] + 1.0f);   // +1 = self loop
}

// xh[node][f] = fp16( dinv[node] * x[node][f] )  — float4-granular, stride 100
__global__ __launch_bounds__(256) void k_convx(const float4* __restrict__ x4,
                                               const float* __restrict__ dinv,
                                               uint2* __restrict__ xh4, int total4) {
  int i = blockIdx.x * 256 + threadIdx.x;
  if (i < total4) {
    int node = i / 25;                 // 25 float4 per 100-f row
    float d = dinv[node];
    float4 v = x4[i];
    union { uint2 u; __half2 h[2]; } p;
    p.h[0] = __halves2half2(__float2half_rn(d * v.x), __float2half_rn(d * v.y));
    p.h[1] = __halves2half2(__float2half_rn(d * v.z), __float2half_rn(d * v.w));
    xh4[i] = p.u;
  }
}

// Wt[nn][k] = fp16(W[k][nn]) for k < Kreal else 0.   Wt: [N][128]
__global__ __launch_bounds__(256) void k_convw(const float* __restrict__ W,
                                               _Float16* __restrict__ Wt,
                                               int N, int Kreal, int total) {
  int i = blockIdx.x * 256 + threadIdx.x;
  if (i < total) {
    int nn = i >> 7, k = i & 127;
    Wt[i] = (k < Kreal) ? (_Float16)W[k * N + nn] : (_Float16)0.f;
  }
}

// ---------------- prefix scan (3 kernels), 1024 elements/block -------------
__global__ __launch_bounds__(256) void k_scan1(const int* __restrict__ deg,
                                               int* __restrict__ local,
                                               int* __restrict__ bsum, int n) {
  __shared__ int s[256];
  int tid = threadIdx.x;
  int base = blockIdx.x * 1024 + tid * 4;
  int v0 = (base + 0 < n) ? deg[base + 0] : 0;
  int v1 = (base + 1 < n) ? deg[base + 1] : 0;
  int v2 = (base + 2 < n) ? deg[base + 2] : 0;
  int v3 = (base + 3 < n) ? deg[base + 3] : 0;
  int tsum = v0 + v1 + v2 + v3;
  s[tid] = tsum;
  __syncthreads();
#pragma unroll
  for (int off = 1; off < 256; off <<= 1) {
    int t = (tid >= off) ? s[tid - off] : 0;
    __syncthreads();
    s[tid] += t;
    __syncthreads();
  }
  int excl = s[tid] - tsum;
  if (tid == 255) bsum[blockIdx.x] = s[255];
  if (base + 0 < n) local[base + 0] = excl;
  if (base + 1 < n) local[base + 1] = excl + v0;
  if (base + 2 < n) local[base + 2] = excl + v0 + v1;
  if (base + 3 < n) local[base + 3] = excl + v0 + v1 + v2;
}

__global__ __launch_bounds__(256) void k_scan2(int* __restrict__ bsum, int nb) {
  __shared__ int s[256];
  int tid = threadIdx.x;
  int v = (tid < nb) ? bsum[tid] : 0;
  s[tid] = v;
  __syncthreads();
#pragma unroll
  for (int off = 1; off < 256; off <<= 1) {
    int t = (tid >= off) ? s[tid - off] : 0;
    __syncthreads();
    s[tid] += t;
    __syncthreads();
  }
  if (tid < nb) bsum[tid] = s[tid] - v;   // exclusive
}

__global__ __launch_bounds__(256) void k_scan3(int* __restrict__ rowstart,
                                               const int* __restrict__ bsum,
                                               int* __restrict__ cursor,
                                               int n, int E) {
  int i = blockIdx.x * 256 + threadIdx.x;
  if (i < n) {
    int v = rowstart[i] + bsum[i >> 10];
    rowstart[i] = v;
    cursor[i] = v;
  }
  if (i == n) rowstart[n] = E;
}

// CSR fill: csr[pos] = src node id (ushort)
__global__ __launch_bounds__(256) void k_fill(const void* __restrict__ ei,
                                              const int* __restrict__ mode,
                                              int* __restrict__ cursor,
                                              unsigned short* __restrict__ csr, int E) {
  int i = blockIdx.x * 256 + threadIdx.x;
  if (i < E) {
    int m = *mode;
    int r = edge_at(ei, m, i);
    int c = edge_at(ei, m, E + i);
    int pos = atomicAdd(&cursor[c], 1);
    csr[pos] = (unsigned short)r;
  }
}

// ---------------------------------------------------------------------------
__device__ __forceinline__ float4 h4_to_f4(uint2 u) {
  union { uint2 u; __half2 h[2]; } p; p.u = u;
  float2 a = __half22float2(p.h[0]);
  float2 b = __half22float2(p.h[1]);
  return make_float4(a.x, a.y, b.x, b.y);
}

// Layer-1 pull: aggh[c][0..99] = fp16( dinv[c] * (xh[c] + sum_{edges} xh[r]) )
// OUTPUT stride 128 (cols 100..127 zeroed for the MFMA K-pad).
// 25 lanes/node, 4 halves (8 B) per lane. 10 nodes per 256-thread block.
__global__ __launch_bounds__(256) void k_pull1(const int* __restrict__ rowstart,
                                               const unsigned short* __restrict__ csr,
                                               const uint2* __restrict__ xh4,
                                               const float* __restrict__ dinv,
                                               uint2* __restrict__ aggh4, int n) {
  int g = threadIdx.x / 25;
  int lane = threadIdx.x - g * 25;
  if (g >= 10) return;
  int node = blockIdx.x * 10 + g;
  if (node >= n) return;

  float4 acc = h4_to_f4(xh4[node * 25 + lane]);    // self term (dinv[c]*x[c])
  int beg = rowstart[node], end = rowstart[node + 1];
  int j = beg;
  for (; j + 1 < end; j += 2) {
    int r0 = csr[j], r1 = csr[j + 1];
    float4 a = h4_to_f4(xh4[r0 * 25 + lane]);
    float4 b = h4_to_f4(xh4[r1 * 25 + lane]);
    acc.x += a.x + b.x; acc.y += a.y + b.y;
    acc.z += a.z + b.z; acc.w += a.w + b.w;
  }
  if (j < end) {
    float4 a = h4_to_f4(xh4[(int)csr[j] * 25 + lane]);
    acc.x += a.x; acc.y += a.y; acc.z += a.z; acc.w += a.w;
  }
  float d = dinv[node];
  union { uint2 u; __half2 h[2]; } p;
  p.h[0] = __halves2half2(__float2half_rn(d * acc.x), __float2half_rn(d * acc.y));
  p.h[1] = __halves2half2(__float2half_rn(d * acc.z), __float2half_rn(d * acc.w));
  aggh4[node * 32 + lane] = p.u;
  if (lane < 7) aggh4[node * 32 + 25 + lane] = make_uint2(0u, 0u);  // K-pad
}

// Layer-2 pull: out[c] = dinv[c] * (th[c] + sum th[r]) + b2
// 8 lanes/node, 8 halves (16 B) per lane. 32 nodes per 256-thread block.
__global__ __launch_bounds__(256) void k_pull2(const int* __restrict__ rowstart,
                                               const unsigned short* __restrict__ csr,
                                               const uint4* __restrict__ th4,
                                               const float* __restrict__ dinv,
                                               const float4* __restrict__ b2_4,
                                               float4* __restrict__ out4, int n) {
  int g = threadIdx.x >> 3;
  int lane = threadIdx.x & 7;
  int node = blockIdx.x * 32 + g;
  if (node >= n) return;

  uint4 sv = th4[node * 8 + lane];
  float4 acc0 = h4_to_f4(make_uint2(sv.x, sv.y));
  float4 acc1 = h4_to_f4(make_uint2(sv.z, sv.w));

  int beg = rowstart[node], end = rowstart[node + 1];
  int j = beg;
  for (; j + 1 < end; j += 2) {
    uint4 u0 = th4[(int)csr[j] * 8 + lane];
    uint4 u1 = th4[(int)csr[j + 1] * 8 + lane];
    float4 a0 = h4_to_f4(make_uint2(u0.x, u0.y));
    float4 a1 = h4_to_f4(make_uint2(u0.z, u0.w));
    float4 b0 = h4_to_f4(make_uint2(u1.x, u1.y));
    float4 b1 = h4_to_f4(make_uint2(u1.z, u1.w));
    acc0.x += a0.x + b0.x; acc0.y += a0.y + b0.y;
    acc0.z += a0.z + b0.z; acc0.w += a0.w + b0.w;
    acc1.x += a1.x + b1.x; acc1.y += a1.y + b1.y;
    acc1.z += a1.z + b1.z; acc1.w += a1.w + b1.w;
  }
  if (j < end) {
    uint4 u0 = th4[(int)csr[j] * 8 + lane];
    float4 a0 = h4_to_f4(make_uint2(u0.x, u0.y));
    float4 a1 = h4_to_f4(make_uint2(u0.z, u0.w));
    acc0.x += a0.x; acc0.y += a0.y; acc0.z += a0.z; acc0.w += a0.w;
    acc1.x += a1.x; acc1.y += a1.y; acc1.z += a1.z; acc1.w += a1.w;
  }
  float d = dinv[node];
  float4 bb0 = b2_4[lane * 2], bb1 = b2_4[lane * 2 + 1];
  out4[node * 16 + lane * 2]     = make_float4(d * acc0.x + bb0.x, d * acc0.y + bb0.y,
                                               d * acc0.z + bb0.z, d * acc0.w + bb0.w);
  out4[node * 16 + lane * 2 + 1] = make_float4(d * acc1.x + bb1.x, d * acc1.y + bb1.y,
                                               d * acc1.z + bb1.z, d * acc1.w + bb1.w);
}

// ---------------------------------------------------------------------------
// MFMA GEMM: Y[n][NT*16] = f( A[n][128] @ W ), W given as Wt[NT*16][128] (B^T).
// One wave per 16-row strip; B-fragments + bias hoisted; no LDS.
// mfma_f32_16x16x32_f16: A row=lane&15, k=(lane>>4)*8+j (8 contiguous halves);
// B col=lane&15 (from Wt row), same k; C/D col=lane&15, row=(lane>>4)*4+reg.
// ---------------------------------------------------------------------------
template <int NT, bool RELU, bool SCALE>
__global__ __launch_bounds__(256) void k_gemm(const _Float16* __restrict__ A,
                                              const _Float16* __restrict__ Wt,
                                              const float* __restrict__ bias,
                                              const float* __restrict__ dinv,
                                              _Float16* __restrict__ Y, int n) {
  const int wid = threadIdx.x >> 6;
  const int lane = threadIdx.x & 63;
  const int lr = lane & 15;
  const int lk = lane >> 4;

  half8 b[NT][4];
#pragma unroll
  for (int nt = 0; nt < NT; ++nt)
#pragma unroll
    for (int ks = 0; ks < 4; ++ks)
      b[nt][ks] = *(const half8*)&Wt[(nt * 16 + lr) * 128 + ks * 32 + lk * 8];

  float bs[NT];
#pragma unroll
  for (int nt = 0; nt < NT; ++nt) bs[nt] = bias ? bias[nt * 16 + lr] : 0.f;

  const int nstrips = (n + 15) >> 4;
  for (int s = blockIdx.x * 4 + wid; s < nstrips; s += gridDim.x * 4) {
    const int arow = s * 16 + lr;
    half8 a[4];
#pragma unroll
    for (int ks = 0; ks < 4; ++ks)
      a[ks] = (arow < n) ? *(const half8*)&A[(size_t)arow * 128 + ks * 32 + lk * 8]
                         : half8{0,0,0,0,0,0,0,0};

    f32x4 acc[NT];
#pragma unroll
    for (int nt = 0; nt < NT; ++nt) acc[nt] = f32x4{0.f, 0.f, 0.f, 0.f};

#pragma unroll
    for (int ks = 0; ks < 4; ++ks)
#pragma unroll
      for (int nt = 0; nt < NT; ++nt)
        acc[nt] = __builtin_amdgcn_mfma_f32_16x16x32_f16(a[ks], b[nt][ks], acc[nt], 0, 0, 0);

    float sc[4] = {1.f, 1.f, 1.f, 1.f};
    if (SCALE) {
      int rb = s * 16 + lk * 4;
      if (rb + 3 < n) {
        const float4 dv = *(const float4*)&dinv[rb];
        sc[0] = dv.x; sc[1] = dv.y; sc[2] = dv.z; sc[3] = dv.w;
      } else {
#pragma unroll
        for (int r = 0; r < 4; ++r) sc[r] = (rb + r < n) ? dinv[rb + r] : 0.f;
      }
    }
#pragma unroll
    for (int r = 0; r < 4; ++r) {
      const int orow = s * 16 + lk * 4 + r;
      if (orow < n) {
#pragma unroll
        for (int nt = 0; nt < NT; ++nt) {
          float v = acc[nt][r] + bs[nt];
          if (RELU) v = fmaxf(v, 0.f);
          if (SCALE) v *= sc[r];
          Y[(size_t)orow * (NT * 16) + nt * 16 + lr] = (_Float16)v;
        }
      }
    }
  }
}

// ---------------------------------------------------------------------------
extern "C" void kernel_launch(void* const* d_in, const int* in_sizes, int n_in,
                              void* d_out, int out_size, void* d_ws, size_t ws_size,
                              hipStream_t stream) {
  const float* x  = (const float*)d_in[0];
  const void*  ei = d_in[1];
  const float* W1 = (const float*)d_in[2];
  const float* b1 = (const float*)d_in[3];
  const float* W2 = (const float*)d_in[4];
  const float* b2 = (const float*)d_in[5];
  float* out = (float*)d_out;

  const int n = in_sizes[0] / 100;   // 50000 (< 65536: ushort CSR valid)
  const int E = in_sizes[1] / 2;     // 800000
  const int NB = DIV_UP(n, 1024);    // scan blocks (49)

  // byte allocator, 16B-aligned
  char* ws = (char*)d_ws;
  size_t off = 0;
  auto alloc = [&](size_t bytes) { void* p = ws + off; off += (bytes + 15) & ~15ull; return p; };
  int*            mode     = (int*)   alloc(64 * 4);
  int*            deg      = (int*)   alloc((size_t)n * 4);     // reused as cursor
  float*          dinv     = (float*) alloc((size_t)n * 4);
  int*            rowstart = (int*)   alloc(((size_t)n + 4) * 4);
  int*            bsum     = (int*)   alloc(256 * 4);
  unsigned short* csr      = (unsigned short*)alloc((size_t)E * 2);
  _Float16*       xh       = (_Float16*)alloc((size_t)n * 100 * 2);
  _Float16*       aggh     = (_Float16*)alloc((size_t)n * 128 * 2);  // K-padded
  _Float16*       h1h      = (_Float16*)alloc((size_t)n * 128 * 2);
  _Float16*       thh      = (_Float16*)alloc((size_t)n * 64 * 2);
  _Float16*       Wt1h     = (_Float16*)alloc(128 * 128 * 2);
  _Float16*       Wt2h     = (_Float16*)alloc(64 * 128 * 2);
  int*            cursor   = deg;

  k_detect<<<1, 64, 0, stream>>>((const int*)ei, mode);
  hipMemsetAsync(deg, 0, (size_t)n * sizeof(int), stream);
  k_deg<<<DIV_UP(E, 256), 256, 0, stream>>>(ei, mode, deg, E);
  k_dinv<<<DIV_UP(n, 256), 256, 0, stream>>>(deg, dinv, n);
  k_convx<<<DIV_UP(n * 25, 256), 256, 0, stream>>>((const float4*)x, dinv, (uint2*)xh, n * 25);
  k_convw<<<DIV_UP(128 * 128, 256), 256, 0, stream>>>(W1, Wt1h, 128, 100, 128 * 128);
  k_convw<<<DIV_UP(64 * 128, 256), 256, 0, stream>>>(W2, Wt2h, 64, 128, 64 * 128);

  // CSR by destination (ushort source ids)
  k_scan1<<<NB, 256, 0, stream>>>(deg, rowstart, bsum, n);
  k_scan2<<<1, 256, 0, stream>>>(bsum, NB);
  k_scan3<<<DIV_UP(n + 1, 256), 256, 0, stream>>>(rowstart, bsum, cursor, n, E);
  k_fill<<<DIV_UP(E, 256), 256, 0, stream>>>(ei, mode, cursor, csr, E);

  const int nstrips = DIV_UP(n, 16);
  const int gemm_blocks = DIV_UP(nstrips, 8);   // 2 strips per wave

  // Layer 1: pull (fp16, K-padded) -> h1 = relu(agg @ W1 + b1)   [MFMA]
  k_pull1<<<DIV_UP(n, 10), 256, 0, stream>>>(rowstart, csr, (const uint2*)xh, dinv,
                                             (uint2*)aggh, n);
  k_gemm<8, true, false><<<gemm_blocks, 256, 0, stream>>>(aggh, Wt1h, b1, nullptr, h1h, n);

  // Layer 2: th = dinv * (h1 @ W2)   [MFMA], then pull -> out (f32, +b2)
  k_gemm<4, false, true><<<gemm_blocks, 256, 0, stream>>>(h1h, Wt2h, nullptr, dinv, thh, n);
  k_pull2<<<DIV_UP(n, 32), 256, 0, stream>>>(rowstart, csr, (const uint4*)thh, dinv,
                                             (const float4*)b2, (float4*)out, n);
}

// Round 5
// 158.746 us; speedup vs baseline: 4.4426x; 1.1831x over previous
//
#include <hip/hip_runtime.h>
#include <hip/hip_fp16.h>

#define DIV_UP(a,b) (((a)+(b)-1)/(b))

typedef _Float16 half8 __attribute__((ext_vector_type(8)));
typedef float f32x4 __attribute__((ext_vector_type(4)));

// Bucketed CSR build: buckets of 512 destination nodes.
#define BUK_BITS 9
#define BUK_SIZE 512
#define BUK_CAP  12288   // max records/bucket (mean 8163 for E=800K, +45 sigma margin)
#define MAXBUK   128     // LDS array sizing (nbuk = ceil(50000/512) = 98)
#define NBLK_BUCKET 256
#define CHUNK_MAX 3200   // >= ceil(800000/256)

// NOTE: CSR entries are ushort (source node id) — valid because N_NODES=50000 < 65536.

// ---------------------------------------------------------------------------
// Edge-index dtype detection (int64 vs int32).
// ---------------------------------------------------------------------------
__device__ __forceinline__ int edge_at(const void* ei, int mode64, int idx) {
  if (mode64) return (int)((const long long*)ei)[idx];
  return ((const int*)ei)[idx];
}

__global__ void k_detect(const int* __restrict__ ei32, int* __restrict__ mode) {
  int t = threadIdx.x;                 // 64 threads
  int v = ei32[2 * t + 1];
  unsigned long long b = __ballot(v == 0);
  if (t == 0) *mode = (b == ~0ull) ? 1 : 0;
}

__global__ void k_binit(int* __restrict__ bcur, int nbuk) {
  int t = threadIdx.x;
  if (t < nbuk) bcur[t] = t * BUK_CAP;
}

// ---------------------------------------------------------------------------
// Phase 1: bucket edges by destination range. Per block: LDS histogram over
// nbuk buckets, one global atomic per (block,bucket) to reserve space, local
// LDS sort, coalesced run write-out. rec = (c<<16) | r.
// ---------------------------------------------------------------------------
__global__ __launch_bounds__(256) void k_bucket(const void* __restrict__ ei,
                                                const int* __restrict__ mode,
                                                int* __restrict__ bcur,
                                                unsigned int* __restrict__ recs,
                                                int E, int nbuk) {
  __shared__ unsigned int lrec[CHUNK_MAX];
  __shared__ unsigned int sorted[CHUNK_MAX];
  __shared__ int hist[MAXBUK], lofs[MAXBUK], gbase[MAXBUK], cur[MAXBUK];

  const int chunk = DIV_UP(E, gridDim.x);
  const int e0 = blockIdx.x * chunk;
  const int cnt = min(E, e0 + chunk) - e0;
  if (cnt <= 0) return;

  for (int i = threadIdx.x; i < nbuk; i += 256) hist[i] = 0;
  __syncthreads();

  const int m = *mode;
  for (int i = threadIdx.x; i < cnt; i += 256) {
    int r = edge_at(ei, m, e0 + i);
    int c = edge_at(ei, m, E + e0 + i);
    unsigned int rec = ((unsigned)c << 16) | (unsigned)r;
    lrec[i] = rec;
    atomicAdd(&hist[c >> BUK_BITS], 1);
  }
  __syncthreads();

  if (threadIdx.x == 0) {            // serial exclusive scan over <=128 buckets
    int run = 0;
    for (int b = 0; b < nbuk; ++b) { lofs[b] = run; run += hist[b]; }
  }
  __syncthreads();
  for (int b = threadIdx.x; b < nbuk; b += 256) {
    gbase[b] = atomicAdd(&bcur[b], hist[b]);
    cur[b] = lofs[b];
  }
  __syncthreads();

  for (int i = threadIdx.x; i < cnt; i += 256) {
    unsigned int rec = lrec[i];
    int b = rec >> (16 + BUK_BITS);
    int p = atomicAdd(&cur[b], 1);
    sorted[p] = rec;
  }
  __syncthreads();

  for (int b = 0; b < nbuk; ++b) {
    int len = hist[b], lo = lofs[b], go = gbase[b];
    for (int i = threadIdx.x; i < len; i += 256) recs[go + i] = sorted[lo + i];
  }
}

// ---------------------------------------------------------------------------
// Per-bucket degree count in LDS (no global atomics) -> deg, dinv.
// ---------------------------------------------------------------------------
__global__ __launch_bounds__(256) void k_bdeg(const int* __restrict__ bcur,
                                              const unsigned int* __restrict__ recs,
                                              int* __restrict__ deg,
                                              float* __restrict__ dinv, int n) {
  __shared__ int h[BUK_SIZE];
  const int b = blockIdx.x;
  const int base = b * BUK_CAP;
  const int cnt = bcur[b] - base;
  const int n0 = b << BUK_BITS;
  const int nn = min(BUK_SIZE, n - n0);

  for (int i = threadIdx.x; i < nn; i += 256) h[i] = 0;
  __syncthreads();
  for (int i = threadIdx.x; i < cnt; i += 256) {
    int cl = (int)(recs[base + i] >> 16) - n0;
    atomicAdd(&h[cl], 1);
  }
  __syncthreads();
  for (int i = threadIdx.x; i < nn; i += 256) {
    deg[n0 + i] = h[i];
    dinv[n0 + i] = rsqrtf((float)h[i] + 1.0f);   // +1 = self loop
  }
}

// xh[node][f] = fp16( dinv[node] * x[node][f] )  — float4-granular, stride 100
__global__ __launch_bounds__(256) void k_convx(const float4* __restrict__ x4,
                                               const float* __restrict__ dinv,
                                               uint2* __restrict__ xh4, int total4) {
  int i = blockIdx.x * 256 + threadIdx.x;
  if (i < total4) {
    int node = i / 25;                 // 25 float4 per 100-f row
    float d = dinv[node];
    float4 v = x4[i];
    union { uint2 u; __half2 h[2]; } p;
    p.h[0] = __halves2half2(__float2half_rn(d * v.x), __float2half_rn(d * v.y));
    p.h[1] = __halves2half2(__float2half_rn(d * v.z), __float2half_rn(d * v.w));
    xh4[i] = p.u;
  }
}

// Wt[nn][k] = fp16(W[k][nn]) for k < Kreal else 0.   Wt: [N][128]
__global__ __launch_bounds__(256) void k_convw(const float* __restrict__ W,
                                               _Float16* __restrict__ Wt,
                                               int N, int Kreal, int total) {
  int i = blockIdx.x * 256 + threadIdx.x;
  if (i < total) {
    int nn = i >> 7, k = i & 127;
    Wt[i] = (k < Kreal) ? (_Float16)W[k * N + nn] : (_Float16)0.f;
  }
}

// ---------------- prefix scan (3 kernels), 1024 elements/block -------------
__global__ __launch_bounds__(256) void k_scan1(const int* __restrict__ deg,
                                               int* __restrict__ local,
                                               int* __restrict__ bsum, int n) {
  __shared__ int s[256];
  int tid = threadIdx.x;
  int base = blockIdx.x * 1024 + tid * 4;
  int v0 = (base + 0 < n) ? deg[base + 0] : 0;
  int v1 = (base + 1 < n) ? deg[base + 1] : 0;
  int v2 = (base + 2 < n) ? deg[base + 2] : 0;
  int v3 = (base + 3 < n) ? deg[base + 3] : 0;
  int tsum = v0 + v1 + v2 + v3;
  s[tid] = tsum;
  __syncthreads();
#pragma unroll
  for (int off = 1; off < 256; off <<= 1) {
    int t = (tid >= off) ? s[tid - off] : 0;
    __syncthreads();
    s[tid] += t;
    __syncthreads();
  }
  int excl = s[tid] - tsum;
  if (tid == 255) bsum[blockIdx.x] = s[255];
  if (base + 0 < n) local[base + 0] = excl;
  if (base + 1 < n) local[base + 1] = excl + v0;
  if (base + 2 < n) local[base + 2] = excl + v0 + v1;
  if (base + 3 < n) local[base + 3] = excl + v0 + v1 + v2;
}

__global__ __launch_bounds__(256) void k_scan2(int* __restrict__ bsum, int nb) {
  __shared__ int s[256];
  int tid = threadIdx.x;
  int v = (tid < nb) ? bsum[tid] : 0;
  s[tid] = v;
  __syncthreads();
#pragma unroll
  for (int off = 1; off < 256; off <<= 1) {
    int t = (tid >= off) ? s[tid - off] : 0;
    __syncthreads();
    s[tid] += t;
    __syncthreads();
  }
  if (tid < nb) bsum[tid] = s[tid] - v;   // exclusive
}

__global__ __launch_bounds__(256) void k_scan3(int* __restrict__ rowstart,
                                               const int* __restrict__ bsum,
                                               int n, int E) {
  int i = blockIdx.x * 256 + threadIdx.x;
  if (i < n) rowstart[i] += bsum[i >> 10];
  if (i == n) rowstart[n] = E;
}

// ---------------------------------------------------------------------------
// Phase 2: per-bucket CSR section built in LDS, streamed out coalesced.
// ---------------------------------------------------------------------------
__global__ __launch_bounds__(256) void k_csrfill(const int* __restrict__ bcur,
                                                 const unsigned int* __restrict__ recs,
                                                 const int* __restrict__ rowstart,
                                                 unsigned short* __restrict__ csr, int n) {
  __shared__ unsigned short lcsr[BUK_CAP];
  __shared__ int curs[BUK_SIZE];
  const int b = blockIdx.x;
  const int base = b * BUK_CAP;
  const int cnt = bcur[b] - base;
  const int n0 = b << BUK_BITS;
  const int nn = min(BUK_SIZE, n - n0);
  const int sec0 = rowstart[n0];

  for (int i = threadIdx.x; i < nn; i += 256) curs[i] = rowstart[n0 + i] - sec0;
  __syncthreads();
  for (int i = threadIdx.x; i < cnt; i += 256) {
    unsigned int rec = recs[base + i];
    int cl = (int)(rec >> 16) - n0;
    int p = atomicAdd(&curs[cl], 1);
    lcsr[p] = (unsigned short)(rec & 0xFFFFu);
  }
  __syncthreads();
  for (int i = threadIdx.x; i < cnt; i += 256) csr[sec0 + i] = lcsr[i];
}

// ---------------------------------------------------------------------------
__device__ __forceinline__ float4 h4_to_f4(uint2 u) {
  union { uint2 u; __half2 h[2]; } p; p.u = u;
  float2 a = __half22float2(p.h[0]);
  float2 b = __half22float2(p.h[1]);
  return make_float4(a.x, a.y, b.x, b.y);
}

// Layer-1 pull: aggh[c][0..99] = fp16( dinv[c] * (xh[c] + sum_{edges} xh[r]) )
// OUTPUT stride 128 (cols 100..127 zeroed for the MFMA K-pad).
__global__ __launch_bounds__(256) void k_pull1(const int* __restrict__ rowstart,
                                               const unsigned short* __restrict__ csr,
                                               const uint2* __restrict__ xh4,
                                               const float* __restrict__ dinv,
                                               uint2* __restrict__ aggh4, int n) {
  int g = threadIdx.x / 25;
  int lane = threadIdx.x - g * 25;
  if (g >= 10) return;
  int node = blockIdx.x * 10 + g;
  if (node >= n) return;

  float4 acc = h4_to_f4(xh4[node * 25 + lane]);    // self term (dinv[c]*x[c])
  int beg = rowstart[node], end = rowstart[node + 1];
  int j = beg;
  for (; j + 1 < end; j += 2) {
    int r0 = csr[j], r1 = csr[j + 1];
    float4 a = h4_to_f4(xh4[r0 * 25 + lane]);
    float4 b = h4_to_f4(xh4[r1 * 25 + lane]);
    acc.x += a.x + b.x; acc.y += a.y + b.y;
    acc.z += a.z + b.z; acc.w += a.w + b.w;
  }
  if (j < end) {
    float4 a = h4_to_f4(xh4[(int)csr[j] * 25 + lane]);
    acc.x += a.x; acc.y += a.y; acc.z += a.z; acc.w += a.w;
  }
  float d = dinv[node];
  union { uint2 u; __half2 h[2]; } p;
  p.h[0] = __halves2half2(__float2half_rn(d * acc.x), __float2half_rn(d * acc.y));
  p.h[1] = __halves2half2(__float2half_rn(d * acc.z), __float2half_rn(d * acc.w));
  aggh4[node * 32 + lane] = p.u;
  if (lane < 7) aggh4[node * 32 + 25 + lane] = make_uint2(0u, 0u);  // K-pad
}

// Layer-2 pull: out[c] = dinv[c] * (th[c] + sum th[r]) + b2
__global__ __launch_bounds__(256) void k_pull2(const int* __restrict__ rowstart,
                                               const unsigned short* __restrict__ csr,
                                               const uint4* __restrict__ th4,
                                               const float* __restrict__ dinv,
                                               const float4* __restrict__ b2_4,
                                               float4* __restrict__ out4, int n) {
  int g = threadIdx.x >> 3;
  int lane = threadIdx.x & 7;
  int node = blockIdx.x * 32 + g;
  if (node >= n) return;

  uint4 sv = th4[node * 8 + lane];
  float4 acc0 = h4_to_f4(make_uint2(sv.x, sv.y));
  float4 acc1 = h4_to_f4(make_uint2(sv.z, sv.w));

  int beg = rowstart[node], end = rowstart[node + 1];
  int j = beg;
  for (; j + 1 < end; j += 2) {
    uint4 u0 = th4[(int)csr[j] * 8 + lane];
    uint4 u1 = th4[(int)csr[j + 1] * 8 + lane];
    float4 a0 = h4_to_f4(make_uint2(u0.x, u0.y));
    float4 a1 = h4_to_f4(make_uint2(u0.z, u0.w));
    float4 b0 = h4_to_f4(make_uint2(u1.x, u1.y));
    float4 b1 = h4_to_f4(make_uint2(u1.z, u1.w));
    acc0.x += a0.x + b0.x; acc0.y += a0.y + b0.y;
    acc0.z += a0.z + b0.z; acc0.w += a0.w + b0.w;
    acc1.x += a1.x + b1.x; acc1.y += a1.y + b1.y;
    acc1.z += a1.z + b1.z; acc1.w += a1.w + b1.w;
  }
  if (j < end) {
    uint4 u0 = th4[(int)csr[j] * 8 + lane];
    float4 a0 = h4_to_f4(make_uint2(u0.x, u0.y));
    float4 a1 = h4_to_f4(make_uint2(u0.z, u0.w));
    acc0.x += a0.x; acc0.y += a0.y; acc0.z += a0.z; acc0.w += a0.w;
    acc1.x += a1.x; acc1.y += a1.y; acc1.z += a1.z; acc1.w += a1.w;
  }
  float d = dinv[node];
  float4 bb0 = b2_4[lane * 2], bb1 = b2_4[lane * 2 + 1];
  out4[node * 16 + lane * 2]     = make_float4(d * acc0.x + bb0.x, d * acc0.y + bb0.y,
                                               d * acc0.z + bb0.z, d * acc0.w + bb0.w);
  out4[node * 16 + lane * 2 + 1] = make_float4(d * acc1.x + bb1.x, d * acc1.y + bb1.y,
                                               d * acc1.z + bb1.z, d * acc1.w + bb1.w);
}

// ---------------------------------------------------------------------------
// MFMA GEMM: Y[n][NT*16] = f( A[n][128] @ W ), W given as Wt[NT*16][128] (B^T).
// ---------------------------------------------------------------------------
template <int NT, bool RELU, bool SCALE>
__global__ __launch_bounds__(256) void k_gemm(const _Float16* __restrict__ A,
                                              const _Float16* __restrict__ Wt,
                                              const float* __restrict__ bias,
                                              const float* __restrict__ dinv,
                                              _Float16* __restrict__ Y, int n) {
  const int wid = threadIdx.x >> 6;
  const int lane = threadIdx.x & 63;
  const int lr = lane & 15;
  const int lk = lane >> 4;

  half8 b[NT][4];
#pragma unroll
  for (int nt = 0; nt < NT; ++nt)
#pragma unroll
    for (int ks = 0; ks < 4; ++ks)
      b[nt][ks] = *(const half8*)&Wt[(nt * 16 + lr) * 128 + ks * 32 + lk * 8];

  float bs[NT];
#pragma unroll
  for (int nt = 0; nt < NT; ++nt) bs[nt] = bias ? bias[nt * 16 + lr] : 0.f;

  const int nstrips = (n + 15) >> 4;
  for (int s = blockIdx.x * 4 + wid; s < nstrips; s += gridDim.x * 4) {
    const int arow = s * 16 + lr;
    half8 a[4];
#pragma unroll
    for (int ks = 0; ks < 4; ++ks)
      a[ks] = (arow < n) ? *(const half8*)&A[(size_t)arow * 128 + ks * 32 + lk * 8]
                         : half8{0,0,0,0,0,0,0,0};

    f32x4 acc[NT];
#pragma unroll
    for (int nt = 0; nt < NT; ++nt) acc[nt] = f32x4{0.f, 0.f, 0.f, 0.f};

#pragma unroll
    for (int ks = 0; ks < 4; ++ks)
#pragma unroll
      for (int nt = 0; nt < NT; ++nt)
        acc[nt] = __builtin_amdgcn_mfma_f32_16x16x32_f16(a[ks], b[nt][ks], acc[nt], 0, 0, 0);

    float sc[4] = {1.f, 1.f, 1.f, 1.f};
    if (SCALE) {
      int rb = s * 16 + lk * 4;
      if (rb + 3 < n) {
        const float4 dv = *(const float4*)&dinv[rb];
        sc[0] = dv.x; sc[1] = dv.y; sc[2] = dv.z; sc[3] = dv.w;
      } else {
#pragma unroll
        for (int r = 0; r < 4; ++r) sc[r] = (rb + r < n) ? dinv[rb + r] : 0.f;
      }
    }
#pragma unroll
    for (int r = 0; r < 4; ++r) {
      const int orow = s * 16 + lk * 4 + r;
      if (orow < n) {
#pragma unroll
        for (int nt = 0; nt < NT; ++nt) {
          float v = acc[nt][r] + bs[nt];
          if (RELU) v = fmaxf(v, 0.f);
          if (SCALE) v *= sc[r];
          Y[(size_t)orow * (NT * 16) + nt * 16 + lr] = (_Float16)v;
        }
      }
    }
  }
}

// ---------------------------------------------------------------------------
extern "C" void kernel_launch(void* const* d_in, const int* in_sizes, int n_in,
                              void* d_out, int out_size, void* d_ws, size_t ws_size,
                              hipStream_t stream) {
  const float* x  = (const float*)d_in[0];
  const void*  ei = d_in[1];
  const float* W1 = (const float*)d_in[2];
  const float* b1 = (const float*)d_in[3];
  const float* W2 = (const float*)d_in[4];
  const float* b2 = (const float*)d_in[5];
  float* out = (float*)d_out;

  const int n = in_sizes[0] / 100;   // 50000 (< 65536: ushort CSR valid)
  const int E = in_sizes[1] / 2;     // 800000
  const int NB = DIV_UP(n, 1024);    // scan blocks (49)
  const int nbuk = DIV_UP(n, BUK_SIZE);  // 98

  // byte allocator, 16B-aligned
  char* ws = (char*)d_ws;
  size_t off = 0;
  auto alloc = [&](size_t bytes) { void* p = ws + off; off += (bytes + 15) & ~15ull; return p; };
  int*            mode     = (int*)   alloc(64 * 4);
  int*            bcur     = (int*)   alloc(MAXBUK * 4);
  int*            deg      = (int*)   alloc((size_t)n * 4);
  float*          dinv     = (float*) alloc((size_t)n * 4);
  int*            rowstart = (int*)   alloc(((size_t)n + 4) * 4);
  int*            bsum     = (int*)   alloc(256 * 4);
  unsigned int*   recs     = (unsigned int*)alloc((size_t)nbuk * BUK_CAP * 4);
  unsigned short* csr      = (unsigned short*)alloc((size_t)E * 2);
  _Float16*       xh       = (_Float16*)alloc((size_t)n * 100 * 2);
  _Float16*       aggh     = (_Float16*)alloc((size_t)n * 128 * 2);  // K-padded
  _Float16*       h1h      = (_Float16*)alloc((size_t)n * 128 * 2);
  _Float16*       thh      = (_Float16*)alloc((size_t)n * 64 * 2);
  _Float16*       Wt1h     = (_Float16*)alloc(128 * 128 * 2);
  _Float16*       Wt2h     = (_Float16*)alloc(64 * 128 * 2);

  k_detect<<<1, 64, 0, stream>>>((const int*)ei, mode);
  k_binit<<<1, MAXBUK, 0, stream>>>(bcur, nbuk);
  k_bucket<<<NBLK_BUCKET, 256, 0, stream>>>(ei, mode, bcur, recs, E, nbuk);
  k_bdeg<<<nbuk, 256, 0, stream>>>(bcur, recs, deg, dinv, n);

  k_convx<<<DIV_UP(n * 25, 256), 256, 0, stream>>>((const float4*)x, dinv, (uint2*)xh, n * 25);
  k_convw<<<DIV_UP(128 * 128, 256), 256, 0, stream>>>(W1, Wt1h, 128, 100, 128 * 128);
  k_convw<<<DIV_UP(64 * 128, 256), 256, 0, stream>>>(W2, Wt2h, 64, 128, 64 * 128);

  k_scan1<<<NB, 256, 0, stream>>>(deg, rowstart, bsum, n);
  k_scan2<<<1, 256, 0, stream>>>(bsum, NB);
  k_scan3<<<DIV_UP(n + 1, 256), 256, 0, stream>>>(rowstart, bsum, n, E);
  k_csrfill<<<nbuk, 256, 0, stream>>>(bcur, recs, rowstart, csr, n);

  const int nstrips = DIV_UP(n, 16);
  const int gemm_blocks = DIV_UP(nstrips, 8);   // 2 strips per wave

  // Layer 1: pull (fp16, K-padded) -> h1 = relu(agg @ W1 + b1)   [MFMA]
  k_pull1<<<DIV_UP(n, 10), 256, 0, stream>>>(rowstart, csr, (const uint2*)xh, dinv,
                                             (uint2*)aggh, n);
  k_gemm<8, true, false><<<gemm_blocks, 256, 0, stream>>>(aggh, Wt1h, b1, nullptr, h1h, n);

  // Layer 2: th = dinv * (h1 @ W2)   [MFMA], then pull -> out (f32, +b2)
  k_gemm<4, false, true><<<gemm_blocks, 256, 0, stream>>>(h1h, Wt2h, nullptr, dinv, thh, n);
  k_pull2<<<DIV_UP(n, 32), 256, 0, stream>>>(rowstart, csr, (const uint4*)thh, dinv,
                                             (const float4*)b2, (float4*)out, n);
}

// Round 6
// 132.001 us; speedup vs baseline: 5.3427x; 1.2026x over previous
//
#include <hip/hip_runtime.h>
#include <hip/hip_fp16.h>

#define DIV_UP(a,b) (((a)+(b)-1)/(b))

typedef _Float16 half8 __attribute__((ext_vector_type(8)));
typedef float f32x4 __attribute__((ext_vector_type(4)));

// Bucketed CSR build: buckets of 512 destination nodes.
#define BUK_BITS 9
#define BUK_SIZE 512
#define BUK_CAP  12288   // max records/bucket (mean 8163 for E=800K, huge margin)
#define MAXBUK   128     // nbuk = ceil(50000/512) = 98
#define NBLK_BUCKET 512
#define CHUNK_MAX 1568   // >= ceil(800000/512)

// LDS swizzle for the gemmf strip buffer (halves): spread rows across 16B slots
#define SWZ(row, colh) ((colh) ^ (((row) & 7) << 3))

// NOTE: CSR entries are ushort (source node id) — valid because N_NODES=50000 < 65536.

__device__ __forceinline__ int edge_at(const void* ei, int mode64, int idx) {
  if (mode64) return (int)((const long long*)ei)[idx];
  return ((const int*)ei)[idx];
}

// mode detect (wave 0) + bucket cursor init
__global__ void k_init(const int* __restrict__ ei32, int* __restrict__ mode,
                       int* __restrict__ bcur, int nbuk) {
  int t = threadIdx.x;                 // 128 threads
  if (t < 64) {
    int v = ei32[2 * t + 1];
    unsigned long long b = __ballot(v == 0);
    if (t == 0) *mode = (b == ~0ull) ? 1 : 0;
  }
  if (t < nbuk) bcur[t] = t * BUK_CAP;
}

// ---------------------------------------------------------------------------
// Phase 1: bucket edges by destination range. rec = (c<<16) | r.
// ---------------------------------------------------------------------------
__global__ __launch_bounds__(256) void k_bucket(const void* __restrict__ ei,
                                                const int* __restrict__ mode,
                                                int* __restrict__ bcur,
                                                unsigned int* __restrict__ recs,
                                                int E, int nbuk) {
  __shared__ unsigned int lrec[CHUNK_MAX];
  __shared__ unsigned int sorted[CHUNK_MAX];
  __shared__ int hist[MAXBUK], lofs[MAXBUK], gbase[MAXBUK], cur[MAXBUK];

  const int chunk = DIV_UP(E, gridDim.x);
  const int e0 = blockIdx.x * chunk;
  const int cnt = min(E, e0 + chunk) - e0;
  if (cnt <= 0) return;

  for (int i = threadIdx.x; i < nbuk; i += 256) hist[i] = 0;
  __syncthreads();

  const int m = *mode;
  for (int i = threadIdx.x; i < cnt; i += 256) {
    int r = edge_at(ei, m, e0 + i);
    int c = edge_at(ei, m, E + e0 + i);
    unsigned int rec = ((unsigned)c << 16) | (unsigned)r;
    lrec[i] = rec;
    atomicAdd(&hist[c >> BUK_BITS], 1);
  }
  __syncthreads();

  if (threadIdx.x == 0) {            // serial exclusive scan over <=128 buckets
    int run = 0;
    for (int b = 0; b < nbuk; ++b) { lofs[b] = run; run += hist[b]; }
  }
  __syncthreads();
  for (int b = threadIdx.x; b < nbuk; b += 256) {
    gbase[b] = atomicAdd(&bcur[b], hist[b]);
    cur[b] = lofs[b];
  }
  __syncthreads();

  for (int i = threadIdx.x; i < cnt; i += 256) {
    unsigned int rec = lrec[i];
    int b = rec >> (16 + BUK_BITS);
    int p = atomicAdd(&cur[b], 1);
    sorted[p] = rec;
  }
  __syncthreads();

  // parallel coalesced write-out: position of sorted[i] is gbase[b]+i-lofs[b]
  for (int i = threadIdx.x; i < cnt; i += 256) {
    unsigned int rec = sorted[i];
    int b = rec >> (16 + BUK_BITS);
    recs[gbase[b] + i - lofs[b]] = rec;
  }
}

// ---------------------------------------------------------------------------
// Per-bucket degree hist (LDS) -> dinv + ABSOLUTE rowstart (replaces the old
// k_deg/k_dinv/k_scan1/2/3): bucket base from a tiny scan of bcur counts.
// ---------------------------------------------------------------------------
__global__ __launch_bounds__(256) void k_bdeg(const int* __restrict__ bcur,
                                              const unsigned int* __restrict__ recs,
                                              float* __restrict__ dinv,
                                              int* __restrict__ rowstart,
                                              int n, int E, int nbuk) {
  __shared__ int h[BUK_SIZE];
  __shared__ int psum[256];
  __shared__ int cnts[MAXBUK];
  __shared__ int sbase;
  const int b = blockIdx.x, tid = threadIdx.x;

  if (tid < nbuk) cnts[tid] = bcur[tid] - tid * BUK_CAP;
  h[tid] = 0; h[tid + 256] = 0;
  __syncthreads();
  if (tid == 0) { int s = 0; for (int j = 0; j < b; ++j) s += cnts[j]; sbase = s; }
  const int cnt = cnts[b];
  const int n0 = b << BUK_BITS;
  const int nn = min(BUK_SIZE, n - n0);
  const int base = b * BUK_CAP;

  for (int i = tid; i < cnt; i += 256)
    atomicAdd(&h[(int)(recs[base + i] >> 16) - n0], 1);
  __syncthreads();

  int a0 = h[2 * tid], a1 = h[2 * tid + 1];
  psum[tid] = a0 + a1;
  __syncthreads();
#pragma unroll
  for (int off2 = 1; off2 < 256; off2 <<= 1) {
    int v = (tid >= off2) ? psum[tid - off2] : 0;
    __syncthreads();
    psum[tid] += v;
    __syncthreads();
  }
  int excl = psum[tid] - (a0 + a1);
  int gb = sbase;
  if (2 * tid < nn)     rowstart[n0 + 2 * tid]     = gb + excl;
  if (2 * tid + 1 < nn) rowstart[n0 + 2 * tid + 1] = gb + excl + a0;
  for (int i = tid; i < nn; i += 256)
    dinv[n0 + i] = rsqrtf((float)h[i] + 1.0f);   // +1 = self loop
  if (b == nbuk - 1 && tid == 0) rowstart[n] = E;
}

// xh[node][f] = fp16( dinv[node] * x[node][f] )  — float4-granular, stride 100
__global__ __launch_bounds__(256) void k_convx(const float4* __restrict__ x4,
                                               const float* __restrict__ dinv,
                                               uint2* __restrict__ xh4, int total4) {
  int i = blockIdx.x * 256 + threadIdx.x;
  if (i < total4) {
    int node = i / 25;
    float d = dinv[node];
    float4 v = x4[i];
    union { uint2 u; __half2 h[2]; } p;
    p.h[0] = __halves2half2(__float2half_rn(d * v.x), __float2half_rn(d * v.y));
    p.h[1] = __halves2half2(__float2half_rn(d * v.z), __float2half_rn(d * v.w));
    xh4[i] = p.u;
  }
}

// Both weight transposes in one launch. Wt1:[128][128] (K-pad 100->128), Wt2:[64][128]
__global__ __launch_bounds__(256) void k_convw2(const float* __restrict__ W1,
                                                const float* __restrict__ W2,
                                                _Float16* __restrict__ Wt1,
                                                _Float16* __restrict__ Wt2) {
  int i = blockIdx.x * 256 + threadIdx.x;
  if (i < 128 * 128) {
    int nn = i >> 7, k = i & 127;
    Wt1[i] = (k < 100) ? (_Float16)W1[k * 128 + nn] : (_Float16)0.f;
  } else if (i < 128 * 128 + 64 * 128) {
    int j = i - 128 * 128;
    int nn = j >> 7, k = j & 127;
    Wt2[j] = (_Float16)W2[k * 64 + nn];
  }
}

// ---------------------------------------------------------------------------
// Phase 2: per-bucket CSR section built in LDS, streamed out coalesced.
// ---------------------------------------------------------------------------
__global__ __launch_bounds__(256) void k_csrfill(const int* __restrict__ bcur,
                                                 const unsigned int* __restrict__ recs,
                                                 const int* __restrict__ rowstart,
                                                 unsigned short* __restrict__ csr, int n) {
  __shared__ unsigned short lcsr[BUK_CAP];
  __shared__ int curs[BUK_SIZE];
  const int b = blockIdx.x;
  const int base = b * BUK_CAP;
  const int cnt = bcur[b] - base;
  const int n0 = b << BUK_BITS;
  const int nn = min(BUK_SIZE, n - n0);
  const int sec0 = rowstart[n0];

  for (int i = threadIdx.x; i < nn; i += 256) curs[i] = rowstart[n0 + i] - sec0;
  __syncthreads();
  for (int i = threadIdx.x; i < cnt; i += 256) {
    unsigned int rec = recs[base + i];
    int cl = (int)(rec >> 16) - n0;
    int p = atomicAdd(&curs[cl], 1);
    lcsr[p] = (unsigned short)(rec & 0xFFFFu);
  }
  __syncthreads();
  for (int i = threadIdx.x; i < cnt; i += 256) csr[sec0 + i] = lcsr[i];
}

// ---------------------------------------------------------------------------
__device__ __forceinline__ float4 h4_to_f4(uint2 u) {
  union { uint2 u; __half2 h[2]; } p; p.u = u;
  float2 a = __half22float2(p.h[0]);
  float2 b = __half22float2(p.h[1]);
  return make_float4(a.x, a.y, b.x, b.y);
}
__device__ __forceinline__ void acc_add(float4& acc, float4 a) {
  acc.x += a.x; acc.y += a.y; acc.z += a.z; acc.w += a.w;
}

// Layer-1 pull: aggh[c][0..99] = fp16( dinv[c] * (xh[c] + sum_{edges} xh[r]) )
// OUTPUT stride 128 (cols 100..127 zeroed for the MFMA K-pad). Unroll x4.
__global__ __launch_bounds__(256) void k_pull1(const int* __restrict__ rowstart,
                                               const unsigned short* __restrict__ csr,
                                               const uint2* __restrict__ xh4,
                                               const float* __restrict__ dinv,
                                               uint2* __restrict__ aggh4, int n) {
  int g = threadIdx.x / 25;
  int lane = threadIdx.x - g * 25;
  if (g >= 10) return;
  int node = blockIdx.x * 10 + g;
  if (node >= n) return;

  float4 acc = h4_to_f4(xh4[node * 25 + lane]);    // self term (dinv[c]*x[c])
  int beg = rowstart[node], end = rowstart[node + 1];
  int j = beg;
  for (; j + 3 < end; j += 4) {
    int r0 = csr[j], r1 = csr[j + 1], r2 = csr[j + 2], r3 = csr[j + 3];
    float4 a = h4_to_f4(xh4[r0 * 25 + lane]);
    float4 b = h4_to_f4(xh4[r1 * 25 + lane]);
    float4 c = h4_to_f4(xh4[r2 * 25 + lane]);
    float4 d = h4_to_f4(xh4[r3 * 25 + lane]);
    acc_add(acc, a); acc_add(acc, b); acc_add(acc, c); acc_add(acc, d);
  }
  for (; j < end; ++j) acc_add(acc, h4_to_f4(xh4[(int)csr[j] * 25 + lane]));

  float d = dinv[node];
  union { uint2 u; __half2 h[2]; } p;
  p.h[0] = __halves2half2(__float2half_rn(d * acc.x), __float2half_rn(d * acc.y));
  p.h[1] = __halves2half2(__float2half_rn(d * acc.z), __float2half_rn(d * acc.w));
  aggh4[node * 32 + lane] = p.u;
  if (lane < 7) aggh4[node * 32 + 25 + lane] = make_uint2(0u, 0u);  // K-pad
}

// Layer-2 pull: out[c] = dinv[c] * (th[c] + sum th[r]) + b2.  Unroll x4.
__global__ __launch_bounds__(256) void k_pull2(const int* __restrict__ rowstart,
                                               const unsigned short* __restrict__ csr,
                                               const uint4* __restrict__ th4,
                                               const float* __restrict__ dinv,
                                               const float4* __restrict__ b2_4,
                                               float4* __restrict__ out4, int n) {
  int g = threadIdx.x >> 3;
  int lane = threadIdx.x & 7;
  int node = blockIdx.x * 32 + g;
  if (node >= n) return;

  uint4 sv = th4[node * 8 + lane];
  float4 acc0 = h4_to_f4(make_uint2(sv.x, sv.y));
  float4 acc1 = h4_to_f4(make_uint2(sv.z, sv.w));

  int beg = rowstart[node], end = rowstart[node + 1];
  int j = beg;
  for (; j + 3 < end; j += 4) {
    uint4 u0 = th4[(int)csr[j] * 8 + lane];
    uint4 u1 = th4[(int)csr[j + 1] * 8 + lane];
    uint4 u2 = th4[(int)csr[j + 2] * 8 + lane];
    uint4 u3 = th4[(int)csr[j + 3] * 8 + lane];
    acc_add(acc0, h4_to_f4(make_uint2(u0.x, u0.y)));
    acc_add(acc1, h4_to_f4(make_uint2(u0.z, u0.w)));
    acc_add(acc0, h4_to_f4(make_uint2(u1.x, u1.y)));
    acc_add(acc1, h4_to_f4(make_uint2(u1.z, u1.w)));
    acc_add(acc0, h4_to_f4(make_uint2(u2.x, u2.y)));
    acc_add(acc1, h4_to_f4(make_uint2(u2.z, u2.w)));
    acc_add(acc0, h4_to_f4(make_uint2(u3.x, u3.y)));
    acc_add(acc1, h4_to_f4(make_uint2(u3.z, u3.w)));
  }
  for (; j < end; ++j) {
    uint4 u0 = th4[(int)csr[j] * 8 + lane];
    acc_add(acc0, h4_to_f4(make_uint2(u0.x, u0.y)));
    acc_add(acc1, h4_to_f4(make_uint2(u0.z, u0.w)));
  }
  float d = dinv[node];
  float4 bb0 = b2_4[lane * 2], bb1 = b2_4[lane * 2 + 1];
  out4[node * 16 + lane * 2]     = make_float4(d * acc0.x + bb0.x, d * acc0.y + bb0.y,
                                               d * acc0.z + bb0.z, d * acc0.w + bb0.w);
  out4[node * 16 + lane * 2 + 1] = make_float4(d * acc1.x + bb1.x, d * acc1.y + bb1.y,
                                               d * acc1.z + bb1.z, d * acc1.w + bb1.w);
}

// ---------------------------------------------------------------------------
// Fused MFMA GEMM: per 16-row strip,
//   h1 = relu(aggh @ W1 + b1)      (stays in per-wave LDS, swizzled)
//   thh = dinv * (h1 @ W2)
// A-frag: row=lane&15, k=(lane>>4)*8+j; C/D: col=lane&15, row=(lane>>4)*4+reg.
// n = 50000 is a multiple of 16 -> no partial strips.
// ---------------------------------------------------------------------------
__global__ __launch_bounds__(256, 2) void k_gemmf(const _Float16* __restrict__ A,
                                                  const _Float16* __restrict__ Wt1,
                                                  const float* __restrict__ b1,
                                                  const _Float16* __restrict__ Wt2,
                                                  const float* __restrict__ dinv,
                                                  _Float16* __restrict__ thh, int n) {
  __shared__ __align__(16) _Float16 lds[4][16 * 128];
  const int wid = threadIdx.x >> 6;
  const int lane = threadIdx.x & 63;
  const int lr = lane & 15;
  const int lk = lane >> 4;
  _Float16* myl = lds[wid];

  half8 B1[8][4];
#pragma unroll
  for (int nt = 0; nt < 8; ++nt)
#pragma unroll
    for (int ks = 0; ks < 4; ++ks)
      B1[nt][ks] = *(const half8*)&Wt1[(nt * 16 + lr) * 128 + ks * 32 + lk * 8];
  float bs[8];
#pragma unroll
  for (int nt = 0; nt < 8; ++nt) bs[nt] = b1[nt * 16 + lr];

  const int nstrips = (n + 15) >> 4;
  for (int s = blockIdx.x * 4 + wid; s < nstrips; s += gridDim.x * 4) {
    // ---- layer 1 ----
    const int arow = s * 16 + lr;
    half8 a[4];
#pragma unroll
    for (int ks = 0; ks < 4; ++ks)
      a[ks] = (arow < n) ? *(const half8*)&A[(size_t)arow * 128 + ks * 32 + lk * 8]
                         : half8{0, 0, 0, 0, 0, 0, 0, 0};
    f32x4 acc[8];
#pragma unroll
    for (int nt = 0; nt < 8; ++nt) acc[nt] = f32x4{0.f, 0.f, 0.f, 0.f};
#pragma unroll
    for (int ks = 0; ks < 4; ++ks)
#pragma unroll
      for (int nt = 0; nt < 8; ++nt)
        acc[nt] = __builtin_amdgcn_mfma_f32_16x16x32_f16(a[ks], B1[nt][ks], acc[nt], 0, 0, 0);

    // epilogue 1: relu(acc+bias) -> swizzled LDS strip (row = lk*4+r, col = nt*16+lr)
#pragma unroll
    for (int r = 0; r < 4; ++r) {
      int row = lk * 4 + r;
#pragma unroll
      for (int nt = 0; nt < 8; ++nt)
        myl[row * 128 + SWZ(row, nt * 16 + lr)] =
            (_Float16)fmaxf(acc[nt][r] + bs[nt], 0.f);
    }

    // ---- layer 2 (within-wave LDS dependency; compiler inserts lgkmcnt waits) ----
    half8 B2[4][4];
#pragma unroll
    for (int nt = 0; nt < 4; ++nt)
#pragma unroll
      for (int ks = 0; ks < 4; ++ks)
        B2[nt][ks] = *(const half8*)&Wt2[(nt * 16 + lr) * 128 + ks * 32 + lk * 8];

    half8 a2[4];
#pragma unroll
    for (int ks = 0; ks < 4; ++ks)
      a2[ks] = *(const half8*)&myl[lr * 128 + SWZ(lr, ks * 32 + lk * 8)];

    f32x4 acc2[4];
#pragma unroll
    for (int nt = 0; nt < 4; ++nt) acc2[nt] = f32x4{0.f, 0.f, 0.f, 0.f};
#pragma unroll
    for (int ks = 0; ks < 4; ++ks)
#pragma unroll
      for (int nt = 0; nt < 4; ++nt)
        acc2[nt] = __builtin_amdgcn_mfma_f32_16x16x32_f16(a2[ks], B2[nt][ks], acc2[nt], 0, 0, 0);

    // epilogue 2: dinv scale, store thh
    const int rb = s * 16 + lk * 4;
    float sc[4];
    if (rb + 3 < n) {
      const float4 dv = *(const float4*)&dinv[rb];
      sc[0] = dv.x; sc[1] = dv.y; sc[2] = dv.z; sc[3] = dv.w;
    } else {
#pragma unroll
      for (int r = 0; r < 4; ++r) sc[r] = (rb + r < n) ? dinv[rb + r] : 0.f;
    }
#pragma unroll
    for (int r = 0; r < 4; ++r) {
      const int orow = rb + r;
      if (orow < n) {
#pragma unroll
        for (int nt = 0; nt < 4; ++nt)
          thh[(size_t)orow * 64 + nt * 16 + lr] = (_Float16)(acc2[nt][r] * sc[r]);
      }
    }
  }
}

// ---------------------------------------------------------------------------
extern "C" void kernel_launch(void* const* d_in, const int* in_sizes, int n_in,
                              void* d_out, int out_size, void* d_ws, size_t ws_size,
                              hipStream_t stream) {
  const float* x  = (const float*)d_in[0];
  const void*  ei = d_in[1];
  const float* W1 = (const float*)d_in[2];
  const float* b1 = (const float*)d_in[3];
  const float* W2 = (const float*)d_in[4];
  const float* b2 = (const float*)d_in[5];
  float* out = (float*)d_out;

  const int n = in_sizes[0] / 100;   // 50000 (< 65536: ushort CSR valid; multiple of 16)
  const int E = in_sizes[1] / 2;     // 800000
  const int nbuk = DIV_UP(n, BUK_SIZE);  // 98

  // byte allocator, 16B-aligned
  char* ws = (char*)d_ws;
  size_t off = 0;
  auto alloc = [&](size_t bytes) { void* p = ws + off; off += (bytes + 15) & ~15ull; return p; };
  int*            mode     = (int*)   alloc(64 * 4);
  int*            bcur     = (int*)   alloc(MAXBUK * 4);
  float*          dinv     = (float*) alloc((size_t)n * 4);
  int*            rowstart = (int*)   alloc(((size_t)n + 4) * 4);
  unsigned int*   recs     = (unsigned int*)alloc((size_t)nbuk * BUK_CAP * 4);
  unsigned short* csr      = (unsigned short*)alloc((size_t)E * 2);
  _Float16*       xh       = (_Float16*)alloc((size_t)n * 100 * 2);
  _Float16*       aggh     = (_Float16*)alloc((size_t)n * 128 * 2);  // K-padded
  _Float16*       thh      = (_Float16*)alloc((size_t)n * 64 * 2);
  _Float16*       Wt1h     = (_Float16*)alloc(128 * 128 * 2);
  _Float16*       Wt2h     = (_Float16*)alloc(64 * 128 * 2);

  k_init<<<1, 128, 0, stream>>>((const int*)ei, mode, bcur, nbuk);
  k_bucket<<<NBLK_BUCKET, 256, 0, stream>>>(ei, mode, bcur, recs, E, nbuk);
  k_bdeg<<<nbuk, 256, 0, stream>>>(bcur, recs, dinv, rowstart, n, E, nbuk);

  k_convx<<<DIV_UP(n * 25, 256), 256, 0, stream>>>((const float4*)x, dinv, (uint2*)xh, n * 25);
  k_convw2<<<DIV_UP(128 * 128 + 64 * 128, 256), 256, 0, stream>>>(W1, W2, Wt1h, Wt2h);
  k_csrfill<<<nbuk, 256, 0, stream>>>(bcur, recs, rowstart, csr, n);

  // Layer 1 aggregate -> fused GEMM(relu, dinv) -> Layer 2 aggregate
  k_pull1<<<DIV_UP(n, 10), 256, 0, stream>>>(rowstart, csr, (const uint2*)xh, dinv,
                                             (uint2*)aggh, n);
  const int nstrips = DIV_UP(n, 16);
  k_gemmf<<<DIV_UP(nstrips, 8), 256, 0, stream>>>(aggh, Wt1h, b1, Wt2h, dinv, thh, n);
  k_pull2<<<DIV_UP(n, 32), 256, 0, stream>>>(rowstart, csr, (const uint4*)thh, dinv,
                                             (const float4*)b2, (float4*)out, n);
}

// Round 7
// 119.422 us; speedup vs baseline: 5.9055x; 1.1053x over previous
//
#include <hip/hip_runtime.h>
#include <hip/hip_fp16.h>

#define DIV_UP(a,b) (((a)+(b)-1)/(b))

typedef _Float16 half8 __attribute__((ext_vector_type(8)));
typedef float f32x4 __attribute__((ext_vector_type(4)));

// Bucketed CSR build: buckets of 256 destination nodes.
#define BUK_BITS 8
#define BUK_SIZE 256
#define BUK_CAP  6144    // max real records/bucket (mean 4082, +32 sigma)
#define CSR_CAP  8192    // per-bucket csr section (real + row-pad <= 6144+1792)
#define MAXBUK   256     // nbuk = ceil(50000/256) = 196
#define NBLK_BUCKET 256
#define CHUNK_MAX 3136   // >= ceil(800000/256)

// LDS swizzle for the gemmf strip buffer (halves)
#define SWZ(row, colh) ((colh) ^ (((row) & 7) << 3))

// NOTE: CSR entries are ushort source ids; sentinel = n (50000 < 65536) points
// to an all-zero row so every CSR row can be padded to a multiple of 8.

__device__ __forceinline__ int edge_at(const void* ei, int mode64, int idx) {
  if (mode64) return (int)((const long long*)ei)[idx];
  return ((const int*)ei)[idx];
}

// block 0: mode detect + bucket cursor init; blocks 1..96: weight transposes
__global__ __launch_bounds__(256) void k_init(const int* __restrict__ ei32,
                                              int* __restrict__ mode,
                                              int* __restrict__ bcur, int nbuk,
                                              const float* __restrict__ W1,
                                              const float* __restrict__ W2,
                                              _Float16* __restrict__ Wt1,
                                              _Float16* __restrict__ Wt2) {
  int t = threadIdx.x;
  if (blockIdx.x == 0) {
    if (t < 64) {
      int v = ei32[2 * t + 1];
      unsigned long long b = __ballot(v == 0);
      if (t == 0) *mode = (b == ~0ull) ? 1 : 0;
    }
    if (t < nbuk) bcur[t] = t * BUK_CAP;
  } else {
    int i = (blockIdx.x - 1) * 256 + t;     // 0 .. 24575
    if (i < 128 * 128) {
      int nn = i >> 7, k = i & 127;
      Wt1[i] = (k < 100) ? (_Float16)W1[k * 128 + nn] : (_Float16)0.f;
    } else {
      int j = i - 128 * 128;
      int nn = j >> 7, k = j & 127;
      Wt2[j] = (_Float16)W2[k * 64 + nn];
    }
  }
}

// ---------------------------------------------------------------------------
// Phase 1: bucket edges by destination range. rec = (c<<16) | r.
// ---------------------------------------------------------------------------
__global__ __launch_bounds__(256) void k_bucket(const void* __restrict__ ei,
                                                const int* __restrict__ mode,
                                                int* __restrict__ bcur,
                                                unsigned int* __restrict__ recs,
                                                int E, int nbuk) {
  __shared__ unsigned int lrec[CHUNK_MAX];
  __shared__ unsigned int sorted[CHUNK_MAX];
  __shared__ int hist[MAXBUK], lofs[MAXBUK], gbase[MAXBUK], cur[MAXBUK];

  const int chunk = DIV_UP(E, gridDim.x);
  const int e0 = blockIdx.x * chunk;
  const int cnt = min(E, e0 + chunk) - e0;
  if (cnt <= 0) return;

  for (int i = threadIdx.x; i < nbuk; i += 256) hist[i] = 0;
  __syncthreads();

  const int m = *mode;
  for (int i = threadIdx.x; i < cnt; i += 256) {
    int r = edge_at(ei, m, e0 + i);
    int c = edge_at(ei, m, E + e0 + i);
    unsigned int rec = ((unsigned)c << 16) | (unsigned)r;
    lrec[i] = rec;
    atomicAdd(&hist[c >> BUK_BITS], 1);
  }
  __syncthreads();

  if (threadIdx.x == 0) {            // serial exclusive scan over <=196 buckets
    int run = 0;
    for (int b = 0; b < nbuk; ++b) { lofs[b] = run; run += hist[b]; }
  }
  __syncthreads();
  for (int b = threadIdx.x; b < nbuk; b += 256) {
    gbase[b] = atomicAdd(&bcur[b], hist[b]);
    cur[b] = lofs[b];
  }
  __syncthreads();

  for (int i = threadIdx.x; i < cnt; i += 256) {
    unsigned int rec = lrec[i];
    int b = rec >> (16 + BUK_BITS);
    int p = atomicAdd(&cur[b], 1);
    sorted[p] = rec;
  }
  __syncthreads();

  for (int i = threadIdx.x; i < cnt; i += 256) {
    unsigned int rec = sorted[i];
    int b = rec >> (16 + BUK_BITS);
    recs[gbase[b] + i - lofs[b]] = rec;
  }
}

// ---------------------------------------------------------------------------
// Phase 2 (fused bdeg+csrfill): per bucket of 256 dest nodes —
// hist -> dinv; row lengths padded to x8; rowinfo {beg, plen}; CSR section
// built in LDS (pads = sentinel n), streamed out coalesced at b*CSR_CAP.
// ---------------------------------------------------------------------------
__global__ __launch_bounds__(256) void k_bdeg_fill(const int* __restrict__ bcur,
                                                   const unsigned int* __restrict__ recs,
                                                   float* __restrict__ dinv,
                                                   int2* __restrict__ rowinfo,
                                                   unsigned short* __restrict__ csr,
                                                   int n) {
  __shared__ int h[BUK_SIZE];
  __shared__ int psum[BUK_SIZE];
  __shared__ int curs[BUK_SIZE];
  __shared__ unsigned short lcsr[CSR_CAP];

  const int b = blockIdx.x, tid = threadIdx.x;
  const int base = b * BUK_CAP;
  const int cnt = bcur[b] - base;
  const int n0 = b << BUK_BITS;
  const int nn = min(BUK_SIZE, n - n0);

  h[tid] = 0;
  __syncthreads();
  for (int i = tid; i < cnt; i += 256)
    atomicAdd(&h[(int)(recs[base + i] >> 16) - n0], 1);
  __syncthreads();

  const int deg = h[tid];
  const int plen = (deg + 7) & ~7;          // row padded to multiple of 8
  psum[tid] = plen;
  __syncthreads();
#pragma unroll
  for (int off2 = 1; off2 < 256; off2 <<= 1) {
    int v = (tid >= off2) ? psum[tid - off2] : 0;
    __syncthreads();
    psum[tid] += v;
    __syncthreads();
  }
  const int excl = psum[tid] - plen;
  const int ptot = psum[255];

  if (tid < nn) {
    rowinfo[n0 + tid] = make_int2(b * CSR_CAP + excl, plen);
    dinv[n0 + tid] = rsqrtf((float)deg + 1.0f);   // +1 = self loop
    curs[tid] = excl;
  }
  for (int i = tid; i < ptot; i += 256) lcsr[i] = (unsigned short)n;  // sentinel pads
  __syncthreads();

  for (int i = tid; i < cnt; i += 256) {
    unsigned int rec = recs[base + i];
    int cl = (int)(rec >> 16) - n0;
    int p = atomicAdd(&curs[cl], 1);
    lcsr[p] = (unsigned short)(rec & 0xFFFFu);
  }
  __syncthreads();
  for (int i = tid; i < ptot; i += 256) csr[b * CSR_CAP + i] = lcsr[i];
}

// xh[node][0..99] = fp16(dinv[node]*x[node][*]), row stride 128 halves.
// Last block zeroes the sentinel rows xh[n] and thh[n].
__global__ __launch_bounds__(256) void k_convx(const float4* __restrict__ x4,
                                               const float* __restrict__ dinv,
                                               uint2* __restrict__ xh4,
                                               uint2* __restrict__ thh2,
                                               int n, int total4) {
  int i = blockIdx.x * 256 + threadIdx.x;
  if (i < total4) {
    int node = i / 25;
    int lane = i - node * 25;
    float d = dinv[node];
    float4 v = x4[i];
    union { uint2 u; __half2 h[2]; } p;
    p.h[0] = __halves2half2(__float2half_rn(d * v.x), __float2half_rn(d * v.y));
    p.h[1] = __halves2half2(__float2half_rn(d * v.z), __float2half_rn(d * v.w));
    xh4[(node << 5) + lane] = p.u;
  } else {
    int s = i - total4;                       // sentinel-zero work
    if (s < 32) xh4[(n << 5) + s] = make_uint2(0u, 0u);
    else if (s < 48) thh2[n * 16 + (s - 32)] = make_uint2(0u, 0u);
  }
}

// ---------------------------------------------------------------------------
__device__ __forceinline__ float4 h4_to_f4(uint2 u) {
  union { uint2 u; __half2 h[2]; } p; p.u = u;
  float2 a = __half22float2(p.h[0]);
  float2 b = __half22float2(p.h[1]);
  return make_float4(a.x, a.y, b.x, b.y);
}
__device__ __forceinline__ void acc_add(float4& acc, float4 a) {
  acc.x += a.x; acc.y += a.y; acc.z += a.z; acc.w += a.w;
}

// Layer-1 pull: aggh[c][0..99] = fp16(dinv[c]*(xh[c]+sum xh[r])); rows x8-padded,
// csr chunk of 8 loaded as one uint4. 25 lanes/node, 10 nodes/block.
__global__ __launch_bounds__(256) void k_pull1(const int2* __restrict__ rowinfo,
                                               const unsigned short* __restrict__ csr,
                                               const uint2* __restrict__ xh4,
                                               const float* __restrict__ dinv,
                                               uint2* __restrict__ aggh4, int n) {
  int g = threadIdx.x / 25;
  int lane = threadIdx.x - g * 25;
  if (g >= 10) return;
  int node = blockIdx.x * 10 + g;
  if (node >= n) return;

  float4 acc = h4_to_f4(xh4[(node << 5) + lane]);   // self term
  int2 ri = rowinfo[node];
  int beg = ri.x, end = ri.x + ri.y;
  for (int j = beg; j < end; j += 8) {
    uint4 cw = *(const uint4*)&csr[j];
    int r0 = cw.x & 0xFFFF, r1 = cw.x >> 16;
    int r2 = cw.y & 0xFFFF, r3 = cw.y >> 16;
    int r4 = cw.z & 0xFFFF, r5 = cw.z >> 16;
    int r6 = cw.w & 0xFFFF, r7 = cw.w >> 16;
    float4 t0 = h4_to_f4(xh4[(r0 << 5) + lane]);
    float4 t1 = h4_to_f4(xh4[(r1 << 5) + lane]);
    float4 t2 = h4_to_f4(xh4[(r2 << 5) + lane]);
    float4 t3 = h4_to_f4(xh4[(r3 << 5) + lane]);
    float4 t4 = h4_to_f4(xh4[(r4 << 5) + lane]);
    float4 t5 = h4_to_f4(xh4[(r5 << 5) + lane]);
    float4 t6 = h4_to_f4(xh4[(r6 << 5) + lane]);
    float4 t7 = h4_to_f4(xh4[(r7 << 5) + lane]);
    acc_add(acc, t0); acc_add(acc, t1); acc_add(acc, t2); acc_add(acc, t3);
    acc_add(acc, t4); acc_add(acc, t5); acc_add(acc, t6); acc_add(acc, t7);
  }
  float d = dinv[node];
  union { uint2 u; __half2 h[2]; } p;
  p.h[0] = __halves2half2(__float2half_rn(d * acc.x), __float2half_rn(d * acc.y));
  p.h[1] = __halves2half2(__float2half_rn(d * acc.z), __float2half_rn(d * acc.w));
  aggh4[node * 32 + lane] = p.u;
  if (lane < 7) aggh4[node * 32 + 25 + lane] = make_uint2(0u, 0u);  // K-pad
}

// Layer-2 pull: out[c] = dinv[c]*(th[c]+sum th[r]) + b2. 8 lanes x 16B.
__global__ __launch_bounds__(256) void k_pull2(const int2* __restrict__ rowinfo,
                                               const unsigned short* __restrict__ csr,
                                               const uint4* __restrict__ th4,
                                               const float* __restrict__ dinv,
                                               const float4* __restrict__ b2_4,
                                               float4* __restrict__ out4, int n) {
  int g = threadIdx.x >> 3;
  int lane = threadIdx.x & 7;
  int node = blockIdx.x * 32 + g;
  if (node >= n) return;

  uint4 sv = th4[(node << 3) + lane];
  float4 acc0 = h4_to_f4(make_uint2(sv.x, sv.y));
  float4 acc1 = h4_to_f4(make_uint2(sv.z, sv.w));

  int2 ri = rowinfo[node];
  int beg = ri.x, end = ri.x + ri.y;
  for (int j = beg; j < end; j += 8) {
    uint4 cw = *(const uint4*)&csr[j];
    int r0 = cw.x & 0xFFFF, r1 = cw.x >> 16;
    int r2 = cw.y & 0xFFFF, r3 = cw.y >> 16;
    int r4 = cw.z & 0xFFFF, r5 = cw.z >> 16;
    int r6 = cw.w & 0xFFFF, r7 = cw.w >> 16;
    uint4 u0 = th4[(r0 << 3) + lane];
    uint4 u1 = th4[(r1 << 3) + lane];
    uint4 u2 = th4[(r2 << 3) + lane];
    uint4 u3 = th4[(r3 << 3) + lane];
    uint4 u4 = th4[(r4 << 3) + lane];
    uint4 u5 = th4[(r5 << 3) + lane];
    uint4 u6 = th4[(r6 << 3) + lane];
    uint4 u7 = th4[(r7 << 3) + lane];
    acc_add(acc0, h4_to_f4(make_uint2(u0.x, u0.y)));
    acc_add(acc1, h4_to_f4(make_uint2(u0.z, u0.w)));
    acc_add(acc0, h4_to_f4(make_uint2(u1.x, u1.y)));
    acc_add(acc1, h4_to_f4(make_uint2(u1.z, u1.w)));
    acc_add(acc0, h4_to_f4(make_uint2(u2.x, u2.y)));
    acc_add(acc1, h4_to_f4(make_uint2(u2.z, u2.w)));
    acc_add(acc0, h4_to_f4(make_uint2(u3.x, u3.y)));
    acc_add(acc1, h4_to_f4(make_uint2(u3.z, u3.w)));
    acc_add(acc0, h4_to_f4(make_uint2(u4.x, u4.y)));
    acc_add(acc1, h4_to_f4(make_uint2(u4.z, u4.w)));
    acc_add(acc0, h4_to_f4(make_uint2(u5.x, u5.y)));
    acc_add(acc1, h4_to_f4(make_uint2(u5.z, u5.w)));
    acc_add(acc0, h4_to_f4(make_uint2(u6.x, u6.y)));
    acc_add(acc1, h4_to_f4(make_uint2(u6.z, u6.w)));
    acc_add(acc0, h4_to_f4(make_uint2(u7.x, u7.y)));
    acc_add(acc1, h4_to_f4(make_uint2(u7.z, u7.w)));
  }
  float d = dinv[node];
  float4 bb0 = b2_4[lane * 2], bb1 = b2_4[lane * 2 + 1];
  out4[node * 16 + lane * 2]     = make_float4(d * acc0.x + bb0.x, d * acc0.y + bb0.y,
                                               d * acc0.z + bb0.z, d * acc0.w + bb0.w);
  out4[node * 16 + lane * 2 + 1] = make_float4(d * acc1.x + bb1.x, d * acc1.y + bb1.y,
                                               d * acc1.z + bb1.z, d * acc1.w + bb1.w);
}

// ---------------------------------------------------------------------------
// Fused MFMA GEMM: per 16-row strip, h1 = relu(aggh@W1+b1) (swizzled LDS),
// thh = dinv*(h1@W2).
// ---------------------------------------------------------------------------
__global__ __launch_bounds__(256, 2) void k_gemmf(const _Float16* __restrict__ A,
                                                  const _Float16* __restrict__ Wt1,
                                                  const float* __restrict__ b1,
                                                  const _Float16* __restrict__ Wt2,
                                                  const float* __restrict__ dinv,
                                                  _Float16* __restrict__ thh, int n) {
  __shared__ __align__(16) _Float16 lds[4][16 * 128];
  const int wid = threadIdx.x >> 6;
  const int lane = threadIdx.x & 63;
  const int lr = lane & 15;
  const int lk = lane >> 4;
  _Float16* myl = lds[wid];

  half8 B1[8][4];
#pragma unroll
  for (int nt = 0; nt < 8; ++nt)
#pragma unroll
    for (int ks = 0; ks < 4; ++ks)
      B1[nt][ks] = *(const half8*)&Wt1[(nt * 16 + lr) * 128 + ks * 32 + lk * 8];
  float bs[8];
#pragma unroll
  for (int nt = 0; nt < 8; ++nt) bs[nt] = b1[nt * 16 + lr];

  const int nstrips = (n + 15) >> 4;
  for (int s = blockIdx.x * 4 + wid; s < nstrips; s += gridDim.x * 4) {
    const int arow = s * 16 + lr;
    half8 a[4];
#pragma unroll
    for (int ks = 0; ks < 4; ++ks)
      a[ks] = (arow < n) ? *(const half8*)&A[(size_t)arow * 128 + ks * 32 + lk * 8]
                         : half8{0, 0, 0, 0, 0, 0, 0, 0};
    f32x4 acc[8];
#pragma unroll
    for (int nt = 0; nt < 8; ++nt) acc[nt] = f32x4{0.f, 0.f, 0.f, 0.f};
#pragma unroll
    for (int ks = 0; ks < 4; ++ks)
#pragma unroll
      for (int nt = 0; nt < 8; ++nt)
        acc[nt] = __builtin_amdgcn_mfma_f32_16x16x32_f16(a[ks], B1[nt][ks], acc[nt], 0, 0, 0);

#pragma unroll
    for (int r = 0; r < 4; ++r) {
      int row = lk * 4 + r;
#pragma unroll
      for (int nt = 0; nt < 8; ++nt)
        myl[row * 128 + SWZ(row, nt * 16 + lr)] =
            (_Float16)fmaxf(acc[nt][r] + bs[nt], 0.f);
    }

    half8 B2[4][4];
#pragma unroll
    for (int nt = 0; nt < 4; ++nt)
#pragma unroll
      for (int ks = 0; ks < 4; ++ks)
        B2[nt][ks] = *(const half8*)&Wt2[(nt * 16 + lr) * 128 + ks * 32 + lk * 8];

    half8 a2[4];
#pragma unroll
    for (int ks = 0; ks < 4; ++ks)
      a2[ks] = *(const half8*)&myl[lr * 128 + SWZ(lr, ks * 32 + lk * 8)];

    f32x4 acc2[4];
#pragma unroll
    for (int nt = 0; nt < 4; ++nt) acc2[nt] = f32x4{0.f, 0.f, 0.f, 0.f};
#pragma unroll
    for (int ks = 0; ks < 4; ++ks)
#pragma unroll
      for (int nt = 0; nt < 4; ++nt)
        acc2[nt] = __builtin_amdgcn_mfma_f32_16x16x32_f16(a2[ks], B2[nt][ks], acc2[nt], 0, 0, 0);

    const int rb = s * 16 + lk * 4;
    float sc[4];
    if (rb + 3 < n) {
      const float4 dv = *(const float4*)&dinv[rb];
      sc[0] = dv.x; sc[1] = dv.y; sc[2] = dv.z; sc[3] = dv.w;
    } else {
#pragma unroll
      for (int r = 0; r < 4; ++r) sc[r] = (rb + r < n) ? dinv[rb + r] : 0.f;
    }
#pragma unroll
    for (int r = 0; r < 4; ++r) {
      const int orow = rb + r;
      if (orow < n) {
#pragma unroll
        for (int nt = 0; nt < 4; ++nt)
          thh[(size_t)orow * 64 + nt * 16 + lr] = (_Float16)(acc2[nt][r] * sc[r]);
      }
    }
  }
}

// ---------------------------------------------------------------------------
extern "C" void kernel_launch(void* const* d_in, const int* in_sizes, int n_in,
                              void* d_out, int out_size, void* d_ws, size_t ws_size,
                              hipStream_t stream) {
  const float* x  = (const float*)d_in[0];
  const void*  ei = d_in[1];
  const float* W1 = (const float*)d_in[2];
  const float* b1 = (const float*)d_in[3];
  const float* W2 = (const float*)d_in[4];
  const float* b2 = (const float*)d_in[5];
  float* out = (float*)d_out;

  const int n = in_sizes[0] / 100;   // 50000 (multiple of 16; n < 65536)
  const int E = in_sizes[1] / 2;     // 800000
  const int nbuk = DIV_UP(n, BUK_SIZE);  // 196

  // byte allocator, 16B-aligned
  char* ws = (char*)d_ws;
  size_t off = 0;
  auto alloc = [&](size_t bytes) { void* p = ws + off; off += (bytes + 15) & ~15ull; return p; };
  int*            mode     = (int*)   alloc(64 * 4);
  int*            bcur     = (int*)   alloc(MAXBUK * 4);
  float*          dinv     = (float*) alloc((size_t)n * 4);
  int2*           rowinfo  = (int2*)  alloc((size_t)n * 8);
  unsigned int*   recs     = (unsigned int*)alloc((size_t)nbuk * BUK_CAP * 4);
  unsigned short* csr      = (unsigned short*)alloc((size_t)nbuk * CSR_CAP * 2);
  _Float16*       xh       = (_Float16*)alloc((size_t)(n + 1) * 128 * 2);  // + zero row
  _Float16*       aggh     = (_Float16*)alloc((size_t)n * 128 * 2);        // K-padded
  _Float16*       thh      = (_Float16*)alloc((size_t)(n + 1) * 64 * 2);   // + zero row
  _Float16*       Wt1h     = (_Float16*)alloc(128 * 128 * 2);
  _Float16*       Wt2h     = (_Float16*)alloc(64 * 128 * 2);

  k_init<<<97, 256, 0, stream>>>((const int*)ei, mode, bcur, nbuk, W1, W2, Wt1h, Wt2h);
  k_bucket<<<NBLK_BUCKET, 256, 0, stream>>>(ei, mode, bcur, recs, E, nbuk);
  k_bdeg_fill<<<nbuk, 256, 0, stream>>>(bcur, recs, dinv, rowinfo, csr, n);

  const int total4 = n * 25;
  k_convx<<<DIV_UP(total4 + 48, 256), 256, 0, stream>>>((const float4*)x, dinv,
      (uint2*)xh, (uint2*)thh, n, total4);

  k_pull1<<<DIV_UP(n, 10), 256, 0, stream>>>(rowinfo, csr, (const uint2*)xh, dinv,
                                             (uint2*)aggh, n);
  const int nstrips = DIV_UP(n, 16);
  k_gemmf<<<DIV_UP(nstrips, 8), 256, 0, stream>>>(aggh, Wt1h, b1, Wt2h, dinv, thh, n);
  k_pull2<<<DIV_UP(n, 32), 256, 0, stream>>>(rowinfo, csr, (const uint4*)thh, dinv,
                                             (const float4*)b2, (float4*)out, n);
}